// Round 1
// baseline (8997.789 us; speedup 1.0000x reference)
//
#include <hip/hip_runtime.h>
#include <math.h>

#define BB 8
#define NN 256
#define DD 384
#define LL 6
#define HH 8
#define FFD 1536
#define TT 4
#define DH 48
#define NM1 517      // T + 1 + 2N
#define SS 1034      // 2 * NM1
#define MROWS (BB*SS)

// ---------------------------------------------------------------------------
// Build src (B,S,D) by concatenating the 8 token groups along S.
// s: 0 | 1..256 | 257..512 | 513..516 | 517 | 518..773 | 774..1029 | 1030..1033
// ---------------------------------------------------------------------------
__global__ void build_src(const float* __restrict__ hand_t, const float* __restrict__ head_t,
                          const float* __restrict__ hand_m1, const float* __restrict__ head_m1,
                          const float* __restrict__ state_t, const float* __restrict__ state_m1,
                          const float* __restrict__ tok_m1, const float* __restrict__ tok_t,
                          float* __restrict__ src) {
  int idx = blockIdx.x * 256 + threadIdx.x;
  if (idx >= BB * SS * DD) return;
  int d = idx % DD;
  int bs = idx / DD;
  int s = bs % SS;
  int b = bs / SS;
  float val;
  if (s == 0)               val = state_m1[b * DD + d];
  else if (s <= NN)         val = hand_m1[((size_t)(b * NN + (s - 1))) * DD + d];
  else if (s <= 2 * NN)     val = head_m1[((size_t)(b * NN + (s - 1 - NN))) * DD + d];
  else if (s <= 2 * NN + TT) val = tok_m1[(s - (2 * NN + 1)) * DD + d];
  else if (s == NM1)        val = state_t[b * DD + d];
  else if (s <= NM1 + NN)   val = hand_t[((size_t)(b * NN + (s - NM1 - 1))) * DD + d];
  else if (s <= NM1 + 2 * NN) val = head_t[((size_t)(b * NN + (s - NM1 - 1 - NN))) * DD + d];
  else                      val = tok_t[(s - (NM1 + 2 * NN + 1)) * DD + d];
  src[idx] = val;
}

__global__ void build_coords(const float* __restrict__ c_hand_t, const float* __restrict__ c_head_t,
                             const float* __restrict__ c_hand_m1, const float* __restrict__ c_head_m1,
                             const float* __restrict__ tr_t, const float* __restrict__ tr_m1,
                             float* __restrict__ coords) {
  int idx = blockIdx.x * 256 + threadIdx.x;
  if (idx >= BB * SS * 3) return;
  int a = idx % 3;
  int bs = idx / 3;
  int s = bs % SS;
  int b = bs / SS;
  float val;
  if (s == 0)               val = tr_m1[b * 3 + a];
  else if (s <= NN)         val = c_hand_m1[(b * NN + (s - 1)) * 3 + a];
  else if (s <= 2 * NN)     val = c_head_m1[(b * NN + (s - 1 - NN)) * 3 + a];
  else if (s <= 2 * NN + TT) val = tr_m1[b * 3 + a];
  else if (s == NM1)        val = tr_t[b * 3 + a];
  else if (s <= NM1 + NN)   val = c_hand_t[(b * NN + (s - NM1 - 1)) * 3 + a];
  else if (s <= NM1 + 2 * NN) val = c_head_t[(b * NN + (s - NM1 - 1 - NN)) * 3 + a];
  else                      val = tr_t[b * 3 + a];
  coords[idx] = val;
}

// ---------------------------------------------------------------------------
// Tiled fp32 GEMM: C[m,n] = sum_k A[m,k] * W[n,k] + bias[n]
// (both operands K-contiguous, i.e. "NT" layout). EPI: 0 = bias, 1 = bias+GELU.
// Block = 256 threads, 64x64 tile, BK=16, 4x4 microtile.
// ---------------------------------------------------------------------------
template <int EPI>
__global__ __launch_bounds__(256) void gemm_nt(const float* __restrict__ A,
                                               const float* __restrict__ W,
                                               const float* __restrict__ bias,
                                               float* __restrict__ C,
                                               int M, int N, int K) {
  __shared__ float As[16][64];
  __shared__ float Bs[16][64];
  const int bm = blockIdx.y * 64, bn = blockIdx.x * 64;
  const int tid = threadIdx.x;
  const int tx = tid & 15, ty = tid >> 4;
  const int lr = tid >> 2, lc = (tid & 3) << 2;
  float acc[4][4] = {};
  for (int k0 = 0; k0 < K; k0 += 16) {
    int arow = bm + lr;
    float4 av = make_float4(0.f, 0.f, 0.f, 0.f);
    if (arow < M) av = *(const float4*)(A + (size_t)arow * K + k0 + lc);
    As[lc + 0][lr] = av.x; As[lc + 1][lr] = av.y; As[lc + 2][lr] = av.z; As[lc + 3][lr] = av.w;
    int wrow = bn + lr;
    float4 wv = make_float4(0.f, 0.f, 0.f, 0.f);
    if (wrow < N) wv = *(const float4*)(W + (size_t)wrow * K + k0 + lc);
    Bs[lc + 0][lr] = wv.x; Bs[lc + 1][lr] = wv.y; Bs[lc + 2][lr] = wv.z; Bs[lc + 3][lr] = wv.w;
    __syncthreads();
#pragma unroll
    for (int kk = 0; kk < 16; ++kk) {
      float4 a4 = *(const float4*)&As[kk][ty << 2];
      float4 b4 = *(const float4*)&Bs[kk][tx << 2];
      float a[4] = {a4.x, a4.y, a4.z, a4.w};
      float b[4] = {b4.x, b4.y, b4.z, b4.w};
#pragma unroll
      for (int i = 0; i < 4; ++i)
#pragma unroll
        for (int j = 0; j < 4; ++j) acc[i][j] += a[i] * b[j];
    }
    __syncthreads();
  }
#pragma unroll
  for (int i = 0; i < 4; ++i) {
    int row = bm + (ty << 2) + i;
    if (row >= M) continue;
#pragma unroll
    for (int j = 0; j < 4; ++j) {
      int col = bn + (tx << 2) + j;
      if (col >= N) continue;
      float v = acc[i][j] + bias[col];
      if (EPI == 1) v = 0.5f * v * (1.0f + erff(v * 0.70710678118654752f));
      C[(size_t)row * N + col] = v;
    }
  }
}

// ---------------------------------------------------------------------------
// 3D rotary PE applied in-place to q and k, layout (B,S,D) with head h at
// columns h*48..h*48+47. Per head: 3 axes x (half=8) rotation pairs.
// ---------------------------------------------------------------------------
__global__ void rope_kernel(float* __restrict__ q, float* __restrict__ k,
                            const float* __restrict__ coords) {
  int idx = blockIdx.x * 256 + threadIdx.x;
  const int total = BB * SS * HH * 24;
  if (idx >= total) return;
  int p = idx % 24;
  int rest = idx / 24;
  int h = rest % HH;
  int bs = rest / HH;
  int axis = p >> 3, i = p & 7;
  float cval = coords[bs * 3 + axis];
  // inv_freq[i] = 10000^(-i/8) = exp(-i * ln(10000)/8)
  float inv = expf(-(float)i * 1.1512925464970229f);
  float ang = cval * inv;
  float cs = cosf(ang), sn = sinf(ang);
  size_t base = (size_t)bs * DD + h * DH + axis * 16 + i;
  float x1 = q[base], x2 = q[base + 8];
  q[base]     = x1 * cs - x2 * sn;
  q[base + 8] = x1 * sn + x2 * cs;
  x1 = k[base]; x2 = k[base + 8];
  k[base]     = x1 * cs - x2 * sn;
  k[base + 8] = x1 * sn + x2 * cs;
}

// ---------------------------------------------------------------------------
// Attention: one workgroup = 4 query rows for one (b,h). Two-pass with scores
// in LDS; K/V staged in 64-row chunks (stride 49 pad -> conflict-free).
// Mask: query rows < NM1 attend only keys [0, NM1); rows >= NM1 attend all.
// ---------------------------------------------------------------------------
__global__ __launch_bounds__(256) void attn_kernel(const float* __restrict__ q,
                                                   const float* __restrict__ k,
                                                   const float* __restrict__ v,
                                                   float* __restrict__ out) {
  constexpr int NCH = 17;  // ceil(1034/64)
  __shared__ float qs[4][48];
  __shared__ float sc[4][NCH * 64];
  __shared__ float vs[64][49];
  __shared__ float inv_sum[4];
  const int tid = threadIdx.x;
  const int qb = blockIdx.x;
  const int h = blockIdx.y, b = blockIdx.z;
  const size_t bhb = (size_t)b * SS * DD + h * DH;

  if (tid < 192) {
    int qi = tid / 48, d = tid % 48;
    int qrow = qb * 4 + qi;
    qs[qi][d] = (qrow < SS) ? q[bhb + (size_t)qrow * DD + d] : 0.f;
  }
  __syncthreads();

  // Phase 1: scores. wave g handles query g; lane jj handles key j0+jj.
  const int jj = tid & 63, qi = tid >> 6;
  for (int c = 0; c < NCH; ++c) {
    const int j0 = c * 64;
    for (int l = tid; l < 768; l += 256) {  // 64 rows x 12 float4
      int r = l / 12, cc = (l % 12) * 4;
      int j = j0 + r;
      float4 kv = make_float4(0.f, 0.f, 0.f, 0.f);
      if (j < SS) kv = *(const float4*)(k + bhb + (size_t)j * DD + cc);
      vs[r][cc] = kv.x; vs[r][cc + 1] = kv.y; vs[r][cc + 2] = kv.z; vs[r][cc + 3] = kv.w;
    }
    __syncthreads();
    float dot = 0.f;
#pragma unroll
    for (int d = 0; d < 48; ++d) dot += qs[qi][d] * vs[jj][d];
    sc[qi][j0 + jj] = dot * 0.14433756729740643f;  // 1/sqrt(48)
    __syncthreads();
  }

  // Phase 2: masked softmax, one wave per query.
  {
    const int g = tid >> 6, l = tid & 63;
    int qrow = qb * 4 + g;
    int kmax = (qrow >= SS) ? 0 : ((qrow < NM1) ? NM1 : SS);
    float m = -INFINITY;
    for (int j = l; j < kmax; j += 64) m = fmaxf(m, sc[g][j]);
#pragma unroll
    for (int off = 32; off; off >>= 1) m = fmaxf(m, __shfl_xor(m, off));
    float ssum = 0.f;
    for (int j = l; j < NCH * 64; j += 64) {
      float pv = 0.f;
      if (j < kmax) pv = expf(sc[g][j] - m);
      sc[g][j] = pv;  // zero padding + masked region
      ssum += pv;
    }
#pragma unroll
    for (int off = 32; off; off >>= 1) ssum += __shfl_xor(ssum, off);
    if (l == 0) inv_sum[g] = (kmax > 0) ? (1.f / ssum) : 0.f;
  }
  __syncthreads();

  // Phase 3: out[qi][d] = sum_j p[qi][j] * v[j][d]. Threads 0..191 -> (qi,d).
  float acc = 0.f;
  const int oqi = tid / 48, od = tid % 48;
  for (int c = 0; c < NCH; ++c) {
    const int j0 = c * 64;
    for (int l = tid; l < 768; l += 256) {
      int r = l / 12, cc = (l % 12) * 4;
      int j = j0 + r;
      float4 vv4 = make_float4(0.f, 0.f, 0.f, 0.f);
      if (j < SS) vv4 = *(const float4*)(v + bhb + (size_t)j * DD + cc);
      vs[r][cc] = vv4.x; vs[r][cc + 1] = vv4.y; vs[r][cc + 2] = vv4.z; vs[r][cc + 3] = vv4.w;
    }
    __syncthreads();
    if (tid < 192) {
#pragma unroll
      for (int r = 0; r < 64; ++r) acc += sc[oqi][j0 + r] * vs[r][od];
    }
    __syncthreads();
  }
  if (tid < 192) {
    int qrow = qb * 4 + oqi;
    if (qrow < SS) out[bhb + (size_t)qrow * DD + od] = acc * inv_sum[oqi];
  }
}

// ---------------------------------------------------------------------------
// out = LayerNorm(a + r) * g + be, rows of 384. Block = 128 threads (2 waves).
// ---------------------------------------------------------------------------
__global__ __launch_bounds__(128) void add_ln(const float* __restrict__ a,
                                              const float* __restrict__ r,
                                              const float* __restrict__ g,
                                              const float* __restrict__ be,
                                              float* __restrict__ out) {
  __shared__ float p1[2], p2[2];
  const int row = blockIdx.x;
  const int t = threadIdx.x;
  const size_t base = (size_t)row * DD;
  float x0 = a[base + t] + r[base + t];
  float x1 = a[base + t + 128] + r[base + t + 128];
  float x2 = a[base + t + 256] + r[base + t + 256];
  float s = x0 + x1 + x2;
#pragma unroll
  for (int off = 32; off; off >>= 1) s += __shfl_xor(s, off);
  if ((t & 63) == 0) p1[t >> 6] = s;
  __syncthreads();
  float mean = (p1[0] + p1[1]) * (1.0f / 384.0f);
  float d0 = x0 - mean, d1 = x1 - mean, d2 = x2 - mean;
  float vsum = d0 * d0 + d1 * d1 + d2 * d2;
#pragma unroll
  for (int off = 32; off; off >>= 1) vsum += __shfl_xor(vsum, off);
  if ((t & 63) == 0) p2[t >> 6] = vsum;
  __syncthreads();
  float var = (p2[0] + p2[1]) * (1.0f / 384.0f);
  float rs = rsqrtf(var + 1e-5f);
  out[base + t]       = d0 * rs * g[t]       + be[t];
  out[base + t + 128] = d1 * rs * g[t + 128] + be[t + 128];
  out[base + t + 256] = d2 * rs * g[t + 256] + be[t + 256];
}

__global__ void copy_out(const float* __restrict__ src, float* __restrict__ out) {
  int idx = blockIdx.x * 256 + threadIdx.x;
  if (idx >= BB * TT * DD) return;
  int d = idx % DD;
  int bt = idx / DD;
  int t = bt % TT;
  int b = bt / TT;
  out[idx] = src[((size_t)b * SS + (SS - TT) + t) * DD + d];
}

// ---------------------------------------------------------------------------
extern "C" void kernel_launch(void* const* d_in, const int* in_sizes, int n_in,
                              void* d_out, int out_size, void* d_ws, size_t ws_size,
                              hipStream_t stream) {
  const float* hand_t    = (const float*)d_in[0];
  const float* head_t    = (const float*)d_in[1];
  const float* hand_m1   = (const float*)d_in[2];
  const float* head_m1   = (const float*)d_in[3];
  const float* c_hand_t  = (const float*)d_in[4];
  const float* c_head_t  = (const float*)d_in[5];
  const float* c_hand_m1 = (const float*)d_in[6];
  const float* c_head_m1 = (const float*)d_in[7];
  const float* state_t   = (const float*)d_in[8];
  const float* state_m1  = (const float*)d_in[9];
  const float* tr_t      = (const float*)d_in[10];
  const float* tr_m1     = (const float*)d_in[11];
  const float* tok_m1    = (const float*)d_in[12];
  const float* tok_t     = (const float*)d_in[13];
  const float* Wq = (const float*)d_in[14];
  const float* bq = (const float*)d_in[15];
  const float* Wk = (const float*)d_in[16];
  const float* bk = (const float*)d_in[17];
  const float* Wv = (const float*)d_in[18];
  const float* bv = (const float*)d_in[19];
  const float* Wo = (const float*)d_in[20];
  const float* bo = (const float*)d_in[21];
  const float* W1 = (const float*)d_in[22];
  const float* b1 = (const float*)d_in[23];
  const float* W2 = (const float*)d_in[24];
  const float* b2 = (const float*)d_in[25];
  const float* g1 = (const float*)d_in[26];
  const float* be1 = (const float*)d_in[27];
  const float* g2 = (const float*)d_in[28];
  const float* be2 = (const float*)d_in[29];

  float* ws = (float*)d_ws;
  const size_t SRC_N = (size_t)BB * SS * DD;  // 3,176,448 floats
  float* src    = ws;
  float* coords = src + SRC_N;
  float* qbuf   = coords + (size_t)BB * SS * 3;
  float* kbuf   = qbuf + SRC_N;
  float* vbuf   = kbuf + SRC_N;
  float* tmp    = vbuf + SRC_N;
  float* src2   = tmp + SRC_N;
  float* hbuf   = src2 + SRC_N;  // B*S*FF = 12,705,792 floats

  const int M = MROWS;
  dim3 blk(256);
  build_src<<<(BB * SS * DD + 255) / 256, blk, 0, stream>>>(
      hand_t, head_t, hand_m1, head_m1, state_t, state_m1, tok_m1, tok_t, src);
  build_coords<<<(BB * SS * 3 + 255) / 256, blk, 0, stream>>>(
      c_hand_t, c_head_t, c_hand_m1, c_head_m1, tr_t, tr_m1, coords);

  dim3 g384((DD + 63) / 64, (M + 63) / 64);
  dim3 g1536((FFD + 63) / 64, (M + 63) / 64);
  dim3 gattn((SS + 3) / 4, HH, BB);

  for (int l = 0; l < LL; ++l) {
    const float* Wq_l = Wq + (size_t)l * DD * DD;
    const float* Wk_l = Wk + (size_t)l * DD * DD;
    const float* Wv_l = Wv + (size_t)l * DD * DD;
    const float* Wo_l = Wo + (size_t)l * DD * DD;
    const float* W1_l = W1 + (size_t)l * FFD * DD;
    const float* W2_l = W2 + (size_t)l * DD * FFD;
    const float* bq_l = bq + l * DD;
    const float* bk_l = bk + l * DD;
    const float* bv_l = bv + l * DD;
    const float* bo_l = bo + l * DD;
    const float* b1_l = b1 + l * FFD;
    const float* b2_l = b2 + l * DD;
    const float* g1_l = g1 + l * DD;
    const float* be1_l = be1 + l * DD;
    const float* g2_l = g2 + l * DD;
    const float* be2_l = be2 + l * DD;

    gemm_nt<0><<<g384, blk, 0, stream>>>(src, Wq_l, bq_l, qbuf, M, DD, DD);
    gemm_nt<0><<<g384, blk, 0, stream>>>(src, Wk_l, bk_l, kbuf, M, DD, DD);
    gemm_nt<0><<<g384, blk, 0, stream>>>(src, Wv_l, bv_l, vbuf, M, DD, DD);
    rope_kernel<<<(BB * SS * HH * 24 + 255) / 256, blk, 0, stream>>>(qbuf, kbuf, coords);
    attn_kernel<<<gattn, blk, 0, stream>>>(qbuf, kbuf, vbuf, tmp);
    gemm_nt<0><<<g384, blk, 0, stream>>>(tmp, Wo_l, bo_l, qbuf, M, DD, DD);
    add_ln<<<M, 128, 0, stream>>>(src, qbuf, g1_l, be1_l, src2);
    gemm_nt<1><<<g1536, blk, 0, stream>>>(src2, W1_l, b1_l, hbuf, M, FFD, DD);
    gemm_nt<0><<<g384, blk, 0, stream>>>(hbuf, W2_l, b2_l, kbuf, M, DD, FFD);
    add_ln<<<M, 128, 0, stream>>>(src2, kbuf, g2_l, be2_l, src);
  }
  copy_out<<<(BB * TT * DD + 255) / 256, blk, 0, stream>>>(src, (float*)d_out);
}

// Round 2
// 1872.457 us; speedup vs baseline: 4.8053x; 4.8053x over previous
//
#include <hip/hip_runtime.h>
#include <hip/hip_bf16.h>
#include <math.h>

#define BB 8
#define NN 256
#define DD 384
#define LL 6
#define HH 8
#define FFD 1536
#define TT 4
#define DH 48
#define NM1 517      // T + 1 + 2N
#define SS 1034      // 2 * NM1
#define SSP 1088     // padded key stride for vt (17*64)
#define MROWS (BB*SS)

typedef unsigned short u16;
typedef short bf8 __attribute__((ext_vector_type(8)));
typedef float f32x4 __attribute__((ext_vector_type(4)));

__device__ __forceinline__ u16 f2bf(float f) {
  __hip_bfloat16 h = __float2bfloat16(f);
  return *reinterpret_cast<u16*>(&h);
}
__device__ __forceinline__ float bf2f(u16 u) {
  __hip_bfloat16 h;
  *reinterpret_cast<u16*>(&h) = u;
  return __bfloat162float(h);
}

// ---------------------------------------------------------------------------
// src assembly (fp32), coords assembly — unchanged from round 1 (verified).
// ---------------------------------------------------------------------------
__global__ void build_src(const float* __restrict__ hand_t, const float* __restrict__ head_t,
                          const float* __restrict__ hand_m1, const float* __restrict__ head_m1,
                          const float* __restrict__ state_t, const float* __restrict__ state_m1,
                          const float* __restrict__ tok_m1, const float* __restrict__ tok_t,
                          float* __restrict__ src) {
  int idx = blockIdx.x * 256 + threadIdx.x;
  if (idx >= BB * SS * DD) return;
  int d = idx % DD;
  int bs = idx / DD;
  int s = bs % SS;
  int b = bs / SS;
  float val;
  if (s == 0)               val = state_m1[b * DD + d];
  else if (s <= NN)         val = hand_m1[((size_t)(b * NN + (s - 1))) * DD + d];
  else if (s <= 2 * NN)     val = head_m1[((size_t)(b * NN + (s - 1 - NN))) * DD + d];
  else if (s <= 2 * NN + TT) val = tok_m1[(s - (2 * NN + 1)) * DD + d];
  else if (s == NM1)        val = state_t[b * DD + d];
  else if (s <= NM1 + NN)   val = hand_t[((size_t)(b * NN + (s - NM1 - 1))) * DD + d];
  else if (s <= NM1 + 2 * NN) val = head_t[((size_t)(b * NN + (s - NM1 - 1 - NN))) * DD + d];
  else                      val = tok_t[(s - (NM1 + 2 * NN + 1)) * DD + d];
  src[idx] = val;
}

__global__ void build_coords(const float* __restrict__ c_hand_t, const float* __restrict__ c_head_t,
                             const float* __restrict__ c_hand_m1, const float* __restrict__ c_head_m1,
                             const float* __restrict__ tr_t, const float* __restrict__ tr_m1,
                             float* __restrict__ coords) {
  int idx = blockIdx.x * 256 + threadIdx.x;
  if (idx >= BB * SS * 3) return;
  int a = idx % 3;
  int bs = idx / 3;
  int s = bs % SS;
  int b = bs / SS;
  float val;
  if (s == 0)               val = tr_m1[b * 3 + a];
  else if (s <= NN)         val = c_hand_m1[(b * NN + (s - 1)) * 3 + a];
  else if (s <= 2 * NN)     val = c_head_m1[(b * NN + (s - 1 - NN)) * 3 + a];
  else if (s <= 2 * NN + TT) val = tr_m1[b * 3 + a];
  else if (s == NM1)        val = tr_t[b * 3 + a];
  else if (s <= NM1 + NN)   val = c_hand_t[(b * NN + (s - NM1 - 1)) * 3 + a];
  else if (s <= NM1 + 2 * NN) val = c_head_t[(b * NN + (s - NM1 - 1 - NN)) * 3 + a];
  else                      val = tr_t[b * 3 + a];
  coords[idx] = val;
}

// ---------------------------------------------------------------------------
// fp32 -> bf16 weight conversion (runs once per launch; ~21 MB total)
// ---------------------------------------------------------------------------
__global__ void cvt_bf(const float* __restrict__ in, u16* __restrict__ out, int n4) {
  int idx = blockIdx.x * 256 + threadIdx.x;
  if (idx >= n4) return;
  float4 v = reinterpret_cast<const float4*>(in)[idx];
  short4 o;
  o.x = (short)f2bf(v.x); o.y = (short)f2bf(v.y);
  o.z = (short)f2bf(v.z); o.w = (short)f2bf(v.w);
  reinterpret_cast<short4*>(out)[idx] = o;
}

// zero the padded key columns [SS, SSP) of vt so PV never multiplies garbage
__global__ void pad_vt(u16* __restrict__ vt) {
  int idx = blockIdx.x * 256 + threadIdx.x;
  const int PADW = SSP - SS;
  if (idx >= 64 * DH * PADW) return;
  int c = idx % PADW;
  int rd = idx / PADW;  // (b*8+h)*48 + d
  vt[(size_t)rd * SSP + SS + c] = 0;
}

// ---------------------------------------------------------------------------
// MFMA GEMM: C[m,n] = sum_k A[m,k] * W[n,k] + bias[n]
//   AIN: 0 = A fp32 (converted during LDS staging), 1 = A bf16
//   EPI: 0 = none, 1 = exact GELU
//   OUT: 0 = fp32 row-major, 1 = bf16 per-head (qh layout), 2 = bf16 head-
//        transposed (vt layout), 3 = bf16 row-major
// Tile 128x64, BK=64, 256 threads = 4 waves (2x2), 16x16x32 bf16 MFMA.
// LDS rows are 128 B, XOR-swizzled with ((row&7)<<4) on write AND read.
// ---------------------------------------------------------------------------
template <int AIN, int EPI, int OUT>
__global__ __launch_bounds__(256) void gemm_mfma(
    const float* __restrict__ Af, const u16* __restrict__ Abf,
    const u16* __restrict__ Wb, const float* __restrict__ bias,
    float* __restrict__ Cf, u16* __restrict__ Cb, int M, int N, int K) {
  __shared__ __align__(16) char sm[24576];  // A: 16KB, B: 8KB
  const int tid = threadIdx.x;
  const int bm = blockIdx.y * 128, bn = blockIdx.x * 64;
  const int lid = tid & 63, w = tid >> 6;
  const int wm = w >> 1, wn = w & 1;
  const int l15 = lid & 15, lg = lid >> 4;
  const int r2 = tid >> 1, hf = tid & 1;
  const int arow = (bm + r2 < M) ? (bm + r2) : (M - 1);
  f32x4 acc[4][2] = {};

  for (int k0 = 0; k0 < K; k0 += 64) {
    __syncthreads();
    // ---- stage A tile (128 rows x 64 cols bf16, swizzled) ----
    if (AIN == 0) {
      const float4* gp = reinterpret_cast<const float4*>(Af + (size_t)arow * K + k0 + hf * 32);
      float4 fv[8];
#pragma unroll
      for (int q = 0; q < 8; ++q) fv[q] = gp[q];
#pragma unroll
      for (int q = 0; q < 4; ++q) {
        u16 tb[8] = {f2bf(fv[2 * q].x), f2bf(fv[2 * q].y), f2bf(fv[2 * q].z), f2bf(fv[2 * q].w),
                     f2bf(fv[2 * q + 1].x), f2bf(fv[2 * q + 1].y), f2bf(fv[2 * q + 1].z), f2bf(fv[2 * q + 1].w)};
        int off = ((r2 << 7) + (hf << 6) + (q << 4)) ^ ((r2 & 7) << 4);
        *reinterpret_cast<int4*>(sm + off) = *reinterpret_cast<int4*>(tb);
      }
    } else {
      const int4* gp = reinterpret_cast<const int4*>(Abf + (size_t)arow * K + k0 + hf * 32);
#pragma unroll
      for (int q = 0; q < 4; ++q) {
        int4 v = gp[q];
        int off = ((r2 << 7) + (hf << 6) + (q << 4)) ^ ((r2 & 7) << 4);
        *reinterpret_cast<int4*>(sm + off) = v;
      }
    }
    // ---- stage B tile (64 rows x 64 cols bf16, swizzled) ----
#pragma unroll
    for (int ss2 = 0; ss2 < 2; ++ss2) {
      int s2 = tid * 2 + ss2;
      int brow = s2 >> 3, sl = s2 & 7;
      int4 v = *reinterpret_cast<const int4*>(Wb + (size_t)(bn + brow) * K + k0 + sl * 8);
      int off = 16384 + ((((brow) << 7) + (sl << 4)) ^ ((brow & 7) << 4));
      *reinterpret_cast<int4*>(sm + off) = v;
    }
    __syncthreads();
    // ---- fragments + MFMA ----
    bf8 a[2][4], bfr[2][2];
#pragma unroll
    for (int kf = 0; kf < 2; ++kf) {
#pragma unroll
      for (int mt = 0; mt < 4; ++mt) {
        int row = wm * 64 + mt * 16 + l15;
        int off = ((row << 7) + (kf << 6) + (lg << 4)) ^ ((row & 7) << 4);
        a[kf][mt] = *reinterpret_cast<const bf8*>(sm + off);
      }
#pragma unroll
      for (int nt = 0; nt < 2; ++nt) {
        int row = wn * 32 + nt * 16 + l15;
        int off = 16384 + (((row << 7) + (kf << 6) + (lg << 4)) ^ ((row & 7) << 4));
        bfr[kf][nt] = *reinterpret_cast<const bf8*>(sm + off);
      }
    }
#pragma unroll
    for (int kf = 0; kf < 2; ++kf)
#pragma unroll
      for (int mt = 0; mt < 4; ++mt)
#pragma unroll
        for (int nt = 0; nt < 2; ++nt)
          acc[mt][nt] = __builtin_amdgcn_mfma_f32_16x16x32_bf16(a[kf][mt], bfr[kf][nt], acc[mt][nt], 0, 0, 0);
  }

  // ---- epilogue ----
#pragma unroll
  for (int nt = 0; nt < 2; ++nt) {
    const int n = bn + wn * 32 + nt * 16 + l15;
    const float bsv = bias[n];
    const int hdiv = n / DH, hrem = n % DH;
#pragma unroll
    for (int mt = 0; mt < 4; ++mt) {
      const int m0 = bm + wm * 64 + mt * 16 + lg * 4;
#pragma unroll
      for (int r = 0; r < 4; ++r) {
        int m = m0 + r;
        if (m >= M) continue;
        float v = acc[mt][nt][r] + bsv;
        if (EPI == 1) v = 0.5f * v * (1.0f + erff(v * 0.70710678118654752f));
        if (OUT == 0) {
          Cf[(size_t)m * N + n] = v;
        } else if (OUT == 3) {
          Cb[(size_t)m * N + n] = f2bf(v);
        } else if (OUT == 1) {
          int b = m / SS, s = m - b * SS;
          Cb[((size_t)(b * HH + hdiv) * SS + s) * 64 + hrem] = f2bf(v);
        } else {  // OUT == 2: vt
          int b = m / SS, s = m - b * SS;
          Cb[((size_t)(b * HH + hdiv) * DH + hrem) * SSP + s] = f2bf(v);
        }
      }
    }
  }
}

// ---------------------------------------------------------------------------
// RoPE on bf16 per-head Q/K (in place) + zero the d=48..63 pad.
// ---------------------------------------------------------------------------
__global__ void rope_bf(u16* __restrict__ qh, u16* __restrict__ kh,
                        const float* __restrict__ coords) {
  int idx = blockIdx.x * 256 + threadIdx.x;
  if (idx >= BB * HH * SS * 32) return;
  int j = idx & 31;
  int rest = idx >> 5;  // (b*8+h)*SS + s
  size_t base = (size_t)rest * 64;
  if (j < 24) {
    int s = rest % SS;
    int b = rest / (HH * SS);
    int axis = j >> 3, i = j & 7;
    float cv = coords[((size_t)b * SS + s) * 3 + axis];
    float inv = expf(-(float)i * 1.1512925464970229f);  // 10000^(-i/8)
    float ang = cv * inv;
    float sn = sinf(ang), cs = cosf(ang);
    int d1 = axis * 16 + i;
    float x1 = bf2f(qh[base + d1]), x2 = bf2f(qh[base + d1 + 8]);
    qh[base + d1]     = f2bf(x1 * cs - x2 * sn);
    qh[base + d1 + 8] = f2bf(x1 * sn + x2 * cs);
    x1 = bf2f(kh[base + d1]); x2 = bf2f(kh[base + d1 + 8]);
    kh[base + d1]     = f2bf(x1 * cs - x2 * sn);
    kh[base + d1 + 8] = f2bf(x1 * sn + x2 * cs);
  } else {
    int d = 48 + ((j - 24) << 1);
    qh[base + d] = 0; qh[base + d + 1] = 0;
    kh[base + d] = 0; kh[base + d + 1] = 0;
  }
}

// ---------------------------------------------------------------------------
// Flash attention, bf16 MFMA. One WG = 64 queries for one (b,h); 4 waves x
// 16 queries. Q fragments live in registers across the whole K/V loop.
// K chunk (64x64 bf16) and Vt chunk (48x64 bf16) staged in swizzled LDS;
// P round-trips through per-wave LDS. Online softmax in registers.
// ---------------------------------------------------------------------------
__global__ __launch_bounds__(256) void attn_mfma(const u16* __restrict__ qh,
                                                 const u16* __restrict__ kh,
                                                 const u16* __restrict__ vt,
                                                 float* __restrict__ outp) {
  __shared__ __align__(16) char sm[22528];  // K: 8KB @0, Vt: 6KB @8192, P: 4x2KB @14336
  const int tid = threadIdx.x;
  const int lid = tid & 63, w = tid >> 6;
  const int l15 = lid & 15, lg = lid >> 4;
  const int qblk = blockIdx.x;
  const int h = blockIdx.y, b = blockIdx.z;
  const int bh = b * HH + h;
  const int q0w = qblk * 64 + w * 16;
  const int PB = 14336 + w * 2048;

  // Q fragments (row-clamped)
  bf8 qf[2];
  {
    int row = q0w + l15; if (row >= SS) row = SS - 1;
    const u16* qp = qh + ((size_t)bh * SS + row) * 64;
#pragma unroll
    for (int kf = 0; kf < 2; ++kf)
      qf[kf] = *reinterpret_cast<const bf8*>(qp + kf * 32 + lg * 8);
  }

  float m_r[4], l_r[4];
  f32x4 accO[3] = {};
#pragma unroll
  for (int r = 0; r < 4; ++r) { m_r[r] = -1e30f; l_r[r] = 0.f; }

  const int nch = (qblk < 8) ? 9 : 17;
  for (int c = 0; c < nch; ++c) {
    const int j0 = c * 64;
    __syncthreads();  // previous chunk's LDS reads complete
    // stage K chunk (row-clamped; invalid keys masked later)
#pragma unroll
    for (int ss2 = 0; ss2 < 2; ++ss2) {
      int s2 = tid * 2 + ss2;
      int jj = s2 >> 3, sl = s2 & 7;
      int jrow = j0 + jj; if (jrow >= SS) jrow = SS - 1;
      int4 v = *reinterpret_cast<const int4*>(kh + ((size_t)bh * SS + jrow) * 64 + sl * 8);
      int off = (((jj << 7) + (sl << 4)) ^ ((jj & 7) << 4));
      *reinterpret_cast<int4*>(sm + off) = v;
    }
    // stage Vt chunk (pad columns are zeroed in global)
    for (int s2 = tid; s2 < 384; s2 += 256) {
      int dv = s2 >> 3, sl = s2 & 7;
      int4 v = *reinterpret_cast<const int4*>(vt + ((size_t)bh * DH + dv) * SSP + j0 + sl * 8);
      int off = 8192 + (((dv << 7) + (sl << 4)) ^ ((dv & 7) << 4));
      *reinterpret_cast<int4*>(sm + off) = v;
    }
    __syncthreads();

    // scores: S = Q * K^T  (D rows = q, cols = j)
    f32x4 sv[4];
#pragma unroll
    for (int jt = 0; jt < 4; ++jt) {
      int row = jt * 16 + l15;
      int off0 = ((row << 7) + (lg << 4)) ^ ((row & 7) << 4);
      int off1 = ((row << 7) + 64 + (lg << 4)) ^ ((row & 7) << 4);
      bf8 kb0 = *reinterpret_cast<const bf8*>(sm + off0);
      bf8 kb1 = *reinterpret_cast<const bf8*>(sm + off1);
      f32x4 z = {};
      z = __builtin_amdgcn_mfma_f32_16x16x32_bf16(qf[0], kb0, z, 0, 0, 0);
      z = __builtin_amdgcn_mfma_f32_16x16x32_bf16(qf[1], kb1, z, 0, 0, 0);
      sv[jt] = z;
    }

    // online softmax (row = lg*4 + r, cols across l15 within 16-lane group)
    float pv[4][4], alpha[4];
#pragma unroll
    for (int r = 0; r < 4; ++r) {
      int qrow = q0w + lg * 4 + r;
      float mx = -1e30f;
#pragma unroll
      for (int jt = 0; jt < 4; ++jt) {
        int jcol = j0 + jt * 16 + l15;
        float s = sv[jt][r] * 0.14433756729740643f;  // 1/sqrt(48)
        if (jcol >= SS || (qrow < NM1 && jcol >= NM1)) s = -1e30f;
        sv[jt][r] = s;
        mx = fmaxf(mx, s);
      }
      mx = fmaxf(mx, __shfl_xor(mx, 1));
      mx = fmaxf(mx, __shfl_xor(mx, 2));
      mx = fmaxf(mx, __shfl_xor(mx, 4));
      mx = fmaxf(mx, __shfl_xor(mx, 8));
      float mn = fmaxf(m_r[r], mx);
      alpha[r] = __expf(m_r[r] - mn);
      float ps = 0.f;
#pragma unroll
      for (int jt = 0; jt < 4; ++jt) {
        float p = __expf(sv[jt][r] - mn);
        pv[jt][r] = p;
        ps += p;
      }
      ps += __shfl_xor(ps, 1);
      ps += __shfl_xor(ps, 2);
      ps += __shfl_xor(ps, 4);
      ps += __shfl_xor(ps, 8);
      l_r[r] = l_r[r] * alpha[r] + ps;
      m_r[r] = mn;
    }
#pragma unroll
    for (int dt = 0; dt < 3; ++dt)
#pragma unroll
      for (int r = 0; r < 4; ++r) accO[dt][r] *= alpha[r];

    // write P (bf16) to this wave's LDS region, swizzled
#pragma unroll
    for (int jt = 0; jt < 4; ++jt)
#pragma unroll
      for (int r = 0; r < 4; ++r) {
        int qp = lg * 4 + r;
        int off = ((qp << 7) + ((jt * 16 + l15) << 1)) ^ ((qp & 7) << 4);
        *reinterpret_cast<u16*>(sm + PB + off) = f2bf(pv[jt][r]);
      }
    // read P as A-fragments (same-wave LDS dependence; compiler inserts waits)
    bf8 pa[2];
#pragma unroll
    for (int jc = 0; jc < 2; ++jc) {
      int off = ((l15 << 7) + (jc << 6) + (lg << 4)) ^ ((l15 & 7) << 4);
      pa[jc] = *reinterpret_cast<const bf8*>(sm + PB + off);
    }
    // PV: O += P * V   (B-frag from transposed V tile)
#pragma unroll
    for (int dt = 0; dt < 3; ++dt) {
      int row = dt * 16 + l15;
#pragma unroll
      for (int jc = 0; jc < 2; ++jc) {
        int off = 8192 + (((row << 7) + (jc << 6) + (lg << 4)) ^ ((row & 7) << 4));
        bf8 vb = *reinterpret_cast<const bf8*>(sm + off);
        accO[dt] = __builtin_amdgcn_mfma_f32_16x16x32_bf16(pa[jc], vb, accO[dt], 0, 0, 0);
      }
    }
  }

  // epilogue: divide by softmax denominator, store fp32 (B,S,D)
#pragma unroll
  for (int r = 0; r < 4; ++r) {
    int q = q0w + lg * 4 + r;
    if (q >= SS) continue;
    float inv = 1.0f / l_r[r];
#pragma unroll
    for (int dt = 0; dt < 3; ++dt) {
      int d = dt * 16 + l15;
      outp[((size_t)(b * SS + q)) * DD + h * DH + d] = accO[dt][r] * inv;
    }
  }
}

// ---------------------------------------------------------------------------
// out = LayerNorm(a + r) * g + be (fp32, rows of 384) — unchanged.
// ---------------------------------------------------------------------------
__global__ __launch_bounds__(128) void add_ln(const float* __restrict__ a,
                                              const float* __restrict__ r,
                                              const float* __restrict__ g,
                                              const float* __restrict__ be,
                                              float* __restrict__ out) {
  __shared__ float p1[2], p2[2];
  const int row = blockIdx.x;
  const int t = threadIdx.x;
  const size_t base = (size_t)row * DD;
  float x0 = a[base + t] + r[base + t];
  float x1 = a[base + t + 128] + r[base + t + 128];
  float x2 = a[base + t + 256] + r[base + t + 256];
  float s = x0 + x1 + x2;
#pragma unroll
  for (int off = 32; off; off >>= 1) s += __shfl_xor(s, off);
  if ((t & 63) == 0) p1[t >> 6] = s;
  __syncthreads();
  float mean = (p1[0] + p1[1]) * (1.0f / 384.0f);
  float d0 = x0 - mean, d1 = x1 - mean, d2 = x2 - mean;
  float vsum = d0 * d0 + d1 * d1 + d2 * d2;
#pragma unroll
  for (int off = 32; off; off >>= 1) vsum += __shfl_xor(vsum, off);
  if ((t & 63) == 0) p2[t >> 6] = vsum;
  __syncthreads();
  float var = (p2[0] + p2[1]) * (1.0f / 384.0f);
  float rs = rsqrtf(var + 1e-5f);
  out[base + t]       = d0 * rs * g[t]       + be[t];
  out[base + t + 128] = d1 * rs * g[t + 128] + be[t + 128];
  out[base + t + 256] = d2 * rs * g[t + 256] + be[t + 256];
}

__global__ void copy_out(const float* __restrict__ src, float* __restrict__ out) {
  int idx = blockIdx.x * 256 + threadIdx.x;
  if (idx >= BB * TT * DD) return;
  int d = idx % DD;
  int bt = idx / DD;
  int t = bt % TT;
  int b = bt / TT;
  out[idx] = src[((size_t)b * SS + (SS - TT) + t) * DD + d];
}

// ---------------------------------------------------------------------------
extern "C" void kernel_launch(void* const* d_in, const int* in_sizes, int n_in,
                              void* d_out, int out_size, void* d_ws, size_t ws_size,
                              hipStream_t stream) {
  const float* hand_t    = (const float*)d_in[0];
  const float* head_t    = (const float*)d_in[1];
  const float* hand_m1   = (const float*)d_in[2];
  const float* head_m1   = (const float*)d_in[3];
  const float* c_hand_t  = (const float*)d_in[4];
  const float* c_head_t  = (const float*)d_in[5];
  const float* c_hand_m1 = (const float*)d_in[6];
  const float* c_head_m1 = (const float*)d_in[7];
  const float* state_t   = (const float*)d_in[8];
  const float* state_m1  = (const float*)d_in[9];
  const float* tr_t      = (const float*)d_in[10];
  const float* tr_m1     = (const float*)d_in[11];
  const float* tok_m1    = (const float*)d_in[12];
  const float* tok_t     = (const float*)d_in[13];
  const float* Wq = (const float*)d_in[14];
  const float* bq = (const float*)d_in[15];
  const float* Wk = (const float*)d_in[16];
  const float* bk = (const float*)d_in[17];
  const float* Wv = (const float*)d_in[18];
  const float* bv = (const float*)d_in[19];
  const float* Wo = (const float*)d_in[20];
  const float* bo = (const float*)d_in[21];
  const float* W1 = (const float*)d_in[22];
  const float* b1 = (const float*)d_in[23];
  const float* W2 = (const float*)d_in[24];
  const float* b2 = (const float*)d_in[25];
  const float* g1 = (const float*)d_in[26];
  const float* be1 = (const float*)d_in[27];
  const float* g2 = (const float*)d_in[28];
  const float* be2 = (const float*)d_in[29];

  // workspace layout (fp32 then bf16 regions)
  const size_t SRC_N = (size_t)BB * SS * DD;       // 3,176,448
  float* src    = (float*)d_ws;
  float* src2   = src + SRC_N;
  float* bufA   = src2 + SRC_N;                    // attention output
  float* bufB   = bufA + SRC_N;                    // Wo / FFN2 output
  float* coords = bufB + SRC_N;                    // 24,816
  u16* qh  = (u16*)(coords + (size_t)BB * SS * 3);
  const size_t QH_N = (size_t)BB * HH * SS * 64;   // 4,233,216
  u16* khb = qh + QH_N;
  u16* vtb = khb + QH_N;                           // 64*48*SSP = 3,342,336
  u16* hbf = vtb + (size_t)64 * DH * SSP;          // B*S*FF = 12,705,792
  u16* wbf = hbf + (size_t)MROWS * FFD;
  const size_t WD = (size_t)LL * DD * DD;          // 884,736
  const size_t WF = (size_t)LL * FFD * DD;         // 3,538,944
  u16* wq_bf = wbf;
  u16* wk_bf = wq_bf + WD;
  u16* wv_bf = wk_bf + WD;
  u16* wo_bf = wv_bf + WD;
  u16* w1_bf = wo_bf + WD;
  u16* w2_bf = w1_bf + WF;

  const int M = MROWS;
  dim3 blk(256);

  build_src<<<(BB * SS * DD + 255) / 256, blk, 0, stream>>>(
      hand_t, head_t, hand_m1, head_m1, state_t, state_m1, tok_m1, tok_t, src);
  build_coords<<<(BB * SS * 3 + 255) / 256, blk, 0, stream>>>(
      c_hand_t, c_head_t, c_hand_m1, c_head_m1, tr_t, tr_m1, coords);
  cvt_bf<<<(int)(WD / 4 + 255) / 256, blk, 0, stream>>>(Wq, wq_bf, (int)(WD / 4));
  cvt_bf<<<(int)(WD / 4 + 255) / 256, blk, 0, stream>>>(Wk, wk_bf, (int)(WD / 4));
  cvt_bf<<<(int)(WD / 4 + 255) / 256, blk, 0, stream>>>(Wv, wv_bf, (int)(WD / 4));
  cvt_bf<<<(int)(WD / 4 + 255) / 256, blk, 0, stream>>>(Wo, wo_bf, (int)(WD / 4));
  cvt_bf<<<(int)(WF / 4 + 255) / 256, blk, 0, stream>>>(W1, w1_bf, (int)(WF / 4));
  cvt_bf<<<(int)(WF / 4 + 255) / 256, blk, 0, stream>>>(W2, w2_bf, (int)(WF / 4));
  pad_vt<<<(64 * DH * (SSP - SS) + 255) / 256, blk, 0, stream>>>(vtb);

  dim3 gq(DD / 64, (M + 127) / 128);      // (6, 65)
  dim3 gf1(FFD / 64, (M + 127) / 128);    // (24, 65)
  dim3 gattn((SS + 63) / 64, HH, BB);     // (17, 8, 8)

  for (int l = 0; l < LL; ++l) {
    const u16* Wq_l = wq_bf + (size_t)l * DD * DD;
    const u16* Wk_l = wk_bf + (size_t)l * DD * DD;
    const u16* Wv_l = wv_bf + (size_t)l * DD * DD;
    const u16* Wo_l = wo_bf + (size_t)l * DD * DD;
    const u16* W1_l = w1_bf + (size_t)l * FFD * DD;
    const u16* W2_l = w2_bf + (size_t)l * DD * FFD;
    const float* bq_l = bq + l * DD;
    const float* bk_l = bk + l * DD;
    const float* bv_l = bv + l * DD;
    const float* bo_l = bo + l * DD;
    const float* b1_l = b1 + l * FFD;
    const float* b2_l = b2 + l * DD;

    gemm_mfma<0, 0, 1><<<gq, blk, 0, stream>>>(src, nullptr, Wq_l, bq_l, nullptr, qh, M, DD, DD);
    gemm_mfma<0, 0, 1><<<gq, blk, 0, stream>>>(src, nullptr, Wk_l, bk_l, nullptr, khb, M, DD, DD);
    gemm_mfma<0, 0, 2><<<gq, blk, 0, stream>>>(src, nullptr, Wv_l, bv_l, nullptr, vtb, M, DD, DD);
    rope_bf<<<(BB * HH * SS * 32 + 255) / 256, blk, 0, stream>>>(qh, khb, coords);
    attn_mfma<<<gattn, blk, 0, stream>>>(qh, khb, vtb, bufA);
    gemm_mfma<0, 0, 0><<<gq, blk, 0, stream>>>(bufA, nullptr, Wo_l, bo_l, bufB, nullptr, M, DD, DD);
    add_ln<<<M, 128, 0, stream>>>(src, bufB, g1 + l * DD, be1 + l * DD, src2);
    gemm_mfma<0, 1, 3><<<gf1, blk, 0, stream>>>(src2, nullptr, W1_l, b1_l, nullptr, hbf, M, FFD, DD);
    gemm_mfma<1, 0, 0><<<gq, blk, 0, stream>>>(nullptr, hbf, W2_l, b2_l, bufB, nullptr, M, DD, FFD);
    add_ln<<<M, 128, 0, stream>>>(src2, bufB, g2 + l * DD, be2 + l * DD, src);
  }
  copy_out<<<(BB * TT * DD + 255) / 256, blk, 0, stream>>>(src, (float*)d_out);
}

// Round 3
// 1641.338 us; speedup vs baseline: 5.4820x; 1.1408x over previous
//
#include <hip/hip_runtime.h>
#include <hip/hip_bf16.h>
#include <math.h>

#define BB 8
#define NN 256
#define DD 384
#define LL 6
#define HH 8
#define FFD 1536
#define TT 4
#define DH 48
#define NM1 517      // T + 1 + 2N
#define SS 1034      // 2 * NM1
#define SSP 1088     // padded key stride for vt (17*64)
#define MROWS (BB*SS)
#define NQKV 1152
#define QSCALE 0.14433756729740643f

typedef unsigned short u16;
typedef short bf8 __attribute__((ext_vector_type(8)));
typedef float f32x4 __attribute__((ext_vector_type(4)));

__device__ __forceinline__ u16 f2bf(float f) {
  __hip_bfloat16 h = __float2bfloat16(f);
  return *reinterpret_cast<u16*>(&h);
}
__device__ __forceinline__ float bf2f(u16 u) {
  __hip_bfloat16 h;
  *reinterpret_cast<u16*>(&h) = u;
  return __bfloat162float(h);
}
// async global->LDS, 16B per lane; lds dest must be wave-uniform (HW adds lane*16)
__device__ __forceinline__ void async16(void* lds, const void* g) {
  __builtin_amdgcn_global_load_lds(
      (const __attribute__((address_space(1))) unsigned int*)g,
      (__attribute__((address_space(3))) unsigned int*)lds, 16, 0, 0);
}

// ---------------------------------------------------------------------------
// src assembly: fp32 residual + bf16 mirror.
// ---------------------------------------------------------------------------
__global__ void build_src(const float* __restrict__ hand_t, const float* __restrict__ head_t,
                          const float* __restrict__ hand_m1, const float* __restrict__ head_m1,
                          const float* __restrict__ state_t, const float* __restrict__ state_m1,
                          const float* __restrict__ tok_m1, const float* __restrict__ tok_t,
                          float* __restrict__ src, u16* __restrict__ srcb) {
  int idx = blockIdx.x * 256 + threadIdx.x;
  if (idx >= BB * SS * DD) return;
  int d = idx % DD;
  int bs = idx / DD;
  int s = bs % SS;
  int b = bs / SS;
  float val;
  if (s == 0)               val = state_m1[b * DD + d];
  else if (s <= NN)         val = hand_m1[((size_t)(b * NN + (s - 1))) * DD + d];
  else if (s <= 2 * NN)     val = head_m1[((size_t)(b * NN + (s - 1 - NN))) * DD + d];
  else if (s <= 2 * NN + TT) val = tok_m1[(s - (2 * NN + 1)) * DD + d];
  else if (s == NM1)        val = state_t[b * DD + d];
  else if (s <= NM1 + NN)   val = hand_t[((size_t)(b * NN + (s - NM1 - 1))) * DD + d];
  else if (s <= NM1 + 2 * NN) val = head_t[((size_t)(b * NN + (s - NM1 - 1 - NN))) * DD + d];
  else                      val = tok_t[(s - (NM1 + 2 * NN + 1)) * DD + d];
  src[idx] = val;
  srcb[idx] = f2bf(val);
}

__global__ void build_coords(const float* __restrict__ c_hand_t, const float* __restrict__ c_head_t,
                             const float* __restrict__ c_hand_m1, const float* __restrict__ c_head_m1,
                             const float* __restrict__ tr_t, const float* __restrict__ tr_m1,
                             float* __restrict__ coords) {
  int idx = blockIdx.x * 256 + threadIdx.x;
  if (idx >= BB * SS * 3) return;
  int a = idx % 3;
  int bs = idx / 3;
  int s = bs % SS;
  int b = bs / SS;
  float val;
  if (s == 0)               val = tr_m1[b * 3 + a];
  else if (s <= NN)         val = c_hand_m1[(b * NN + (s - 1)) * 3 + a];
  else if (s <= 2 * NN)     val = c_head_m1[(b * NN + (s - 1 - NN)) * 3 + a];
  else if (s <= 2 * NN + TT) val = tr_m1[b * 3 + a];
  else if (s == NM1)        val = tr_t[b * 3 + a];
  else if (s <= NM1 + NN)   val = c_hand_t[(b * NN + (s - NM1 - 1)) * 3 + a];
  else if (s <= NM1 + 2 * NN) val = c_head_t[(b * NN + (s - NM1 - 1 - NN)) * 3 + a];
  else                      val = tr_t[b * 3 + a];
  coords[idx] = val;
}

// ---------------------------------------------------------------------------
// weight conversion / packing
// ---------------------------------------------------------------------------
__global__ void cvt_bf(const float* __restrict__ in, u16* __restrict__ out, int n4) {
  int idx = blockIdx.x * 256 + threadIdx.x;
  if (idx >= n4) return;
  float4 v = reinterpret_cast<const float4*>(in)[idx];
  short4 o;
  o.x = (short)f2bf(v.x); o.y = (short)f2bf(v.y);
  o.z = (short)f2bf(v.z); o.w = (short)f2bf(v.w);
  reinterpret_cast<short4*>(out)[idx] = o;
}

__global__ void pack_qkv(const float* __restrict__ Wq, const float* __restrict__ Wk,
                         const float* __restrict__ Wv, u16* __restrict__ wqkv) {
  int idx = blockIdx.x * 256 + threadIdx.x;
  const int TOTAL = LL * NQKV * 96;
  if (idx >= TOTAL) return;
  int k4 = idx % 96;
  int n = (idx / 96) % NQKV;
  int l = idx / (96 * NQKV);
  int sel = n / 384, nn = n - sel * 384;
  const float* W = (sel == 0) ? Wq : ((sel == 1) ? Wk : Wv);
  float4 v = *reinterpret_cast<const float4*>(W + ((size_t)l * 384 + nn) * 384 + k4 * 4);
  short4 o;
  o.x = (short)f2bf(v.x); o.y = (short)f2bf(v.y);
  o.z = (short)f2bf(v.z); o.w = (short)f2bf(v.w);
  *reinterpret_cast<short4*>(wqkv + ((size_t)(l * NQKV + n) * 384 + k4 * 4)) = o;
}

__global__ void pack_bqkv(const float* __restrict__ bq, const float* __restrict__ bk,
                          const float* __restrict__ bv, float* __restrict__ bqkv) {
  int idx = blockIdx.x * 256 + threadIdx.x;
  if (idx >= LL * NQKV) return;
  int n = idx % NQKV, l = idx / NQKV;
  int sel = n / 384, nn = n - sel * 384;
  const float* Bp = (sel == 0) ? bq : ((sel == 1) ? bk : bv);
  bqkv[idx] = Bp[l * 384 + nn];
}

// zero the padded key columns [SS, SSP) of vt so PV never multiplies garbage
__global__ void pad_vt(u16* __restrict__ vt) {
  int idx = blockIdx.x * 256 + threadIdx.x;
  const int PADW = SSP - SS;
  if (idx >= 64 * DH * PADW) return;
  int c = idx % PADW;
  int rd = idx / PADW;
  vt[(size_t)rd * SSP + SS + c] = 0;
}

// ---------------------------------------------------------------------------
// MFMA GEMM, bf16 in, async global->LDS staging (m97 structure).
//   C[m,n] = sum_k A[m,k]*W[n,k] + bias[n]
//   EPI: 0 none, 1 exact GELU.
//   OUT: 0 fp32 row-major, 1 bf16 row-major, 2 fused-QKV routing.
// Tile 128x64, BK=64, 4 waves (2x2). LDS layout identical to round 2
// (row-major 128B rows, 16B-unit XOR swizzle) achieved by pre-swizzling
// the GLOBAL source column while keeping the LDS destination linear.
// ---------------------------------------------------------------------------
template <int EPI, int OUT>
__global__ __launch_bounds__(256) void gemm_as(
    const u16* __restrict__ Ab, const u16* __restrict__ Wb,
    const float* __restrict__ bias,
    float* __restrict__ Cf, u16* __restrict__ Cb,
    u16* __restrict__ Ck, u16* __restrict__ Cv,
    int M, int N, int K) {
  __shared__ __align__(16) char sm[24576];  // A 16KB @0, B 8KB @16384
  const int tid = threadIdx.x;
  const int bm = blockIdx.y * 128, bn = blockIdx.x * 64;
  const int lid = tid & 63, w = tid >> 6;
  const int wm = w >> 1, wn = w & 1;
  const int l15 = lid & 15, lg = lid >> 4;
  const int lr = lid >> 3, lu = lid & 7;      // 8-row group: row offset, 16B unit
  const int swz = lu ^ lr;                     // pre-swizzled source unit
  f32x4 acc[4][2] = {};

  for (int k0 = 0; k0 < K; k0 += 64) {
    __syncthreads();
    // A tile: wave w rows [w*32, w*32+32), 4 issues x 1KB
#pragma unroll
    for (int q = 0; q < 4; ++q) {
      int row = w * 32 + q * 8 + lr;
      int grow = bm + row; if (grow >= M) grow = M - 1;
      async16(sm + w * 4096 + q * 1024, Ab + (size_t)grow * K + k0 + (swz << 3));
    }
    // B tile: wave w rows [w*16, w*16+16), 2 issues x 1KB
#pragma unroll
    for (int q = 0; q < 2; ++q) {
      int row = w * 16 + q * 8 + lr;
      async16(sm + 16384 + w * 2048 + q * 1024, Wb + (size_t)(bn + row) * K + k0 + (swz << 3));
    }
    __syncthreads();
    bf8 a[2][4], bfr[2][2];
#pragma unroll
    for (int kf = 0; kf < 2; ++kf) {
#pragma unroll
      for (int mt = 0; mt < 4; ++mt) {
        int row = wm * 64 + mt * 16 + l15;
        int off = ((row << 7) + (kf << 6) + (lg << 4)) ^ ((row & 7) << 4);
        a[kf][mt] = *reinterpret_cast<const bf8*>(sm + off);
      }
#pragma unroll
      for (int nt = 0; nt < 2; ++nt) {
        int row = wn * 32 + nt * 16 + l15;
        int off = 16384 + (((row << 7) + (kf << 6) + (lg << 4)) ^ ((row & 7) << 4));
        bfr[kf][nt] = *reinterpret_cast<const bf8*>(sm + off);
      }
    }
#pragma unroll
    for (int kf = 0; kf < 2; ++kf)
#pragma unroll
      for (int mt = 0; mt < 4; ++mt)
#pragma unroll
        for (int nt = 0; nt < 2; ++nt)
          acc[mt][nt] = __builtin_amdgcn_mfma_f32_16x16x32_bf16(a[kf][mt], bfr[kf][nt], acc[mt][nt], 0, 0, 0);
  }

#pragma unroll
  for (int nt = 0; nt < 2; ++nt) {
    const int n = bn + wn * 32 + nt * 16 + l15;
    const float bsv = bias[n];
#pragma unroll
    for (int mt = 0; mt < 4; ++mt) {
      const int m0 = bm + wm * 64 + mt * 16 + lg * 4;
#pragma unroll
      for (int r = 0; r < 4; ++r) {
        int m = m0 + r;
        if (m >= M) continue;
        float v = acc[mt][nt][r] + bsv;
        if (EPI == 1) v = 0.5f * v * (1.0f + erff(v * 0.70710678118654752f));
        if (OUT == 0) {
          Cf[(size_t)m * N + n] = v;
        } else if (OUT == 1) {
          Cb[(size_t)m * N + n] = f2bf(v);
        } else {  // fused QKV routing
          int bI = m / SS, s = m - bI * SS;
          int sel = n / 384, nn = n - sel * 384;
          int hdiv = nn / DH, hrem = nn - hdiv * DH;
          int bh = bI * HH + hdiv;
          if (sel == 0)      Cb[((size_t)bh * SS + s) * 64 + hrem] = f2bf(v);
          else if (sel == 1) Ck[((size_t)bh * SS + s) * 64 + hrem] = f2bf(v);
          else               Cv[((size_t)bh * DH + hrem) * SSP + s] = f2bf(v);
        }
      }
    }
  }
}

// ---------------------------------------------------------------------------
// RoPE on bf16 per-head Q/K (in place), Q pre-scaled by 1/sqrt(48);
// also zeroes the d=48..63 pad.
// ---------------------------------------------------------------------------
__global__ void rope_bf(u16* __restrict__ qh, u16* __restrict__ kh,
                        const float* __restrict__ coords) {
  int idx = blockIdx.x * 256 + threadIdx.x;
  if (idx >= BB * HH * SS * 32) return;
  int j = idx & 31;
  int rest = idx >> 5;  // (b*8+h)*SS + s
  size_t base = (size_t)rest * 64;
  if (j < 24) {
    int s = rest % SS;
    int b = rest / (HH * SS);
    int axis = j >> 3, i = j & 7;
    float cv = coords[((size_t)b * SS + s) * 3 + axis];
    float inv = expf(-(float)i * 1.1512925464970229f);  // 10000^(-i/8)
    float ang = cv * inv;
    float sn = sinf(ang), cs = cosf(ang);
    int d1 = axis * 16 + i;
    float x1 = bf2f(qh[base + d1]), x2 = bf2f(qh[base + d1 + 8]);
    qh[base + d1]     = f2bf((x1 * cs - x2 * sn) * QSCALE);
    qh[base + d1 + 8] = f2bf((x1 * sn + x2 * cs) * QSCALE);
    x1 = bf2f(kh[base + d1]); x2 = bf2f(kh[base + d1 + 8]);
    kh[base + d1]     = f2bf(x1 * cs - x2 * sn);
    kh[base + d1 + 8] = f2bf(x1 * sn + x2 * cs);
  } else {
    int d = 48 + ((j - 24) << 1);
    qh[base + d] = 0; qh[base + d + 1] = 0;
    kh[base + d] = 0; kh[base + d + 1] = 0;
  }
}

// ---------------------------------------------------------------------------
// Flash attention, bf16 MFMA, NO K/V LDS staging, NO barriers.
// K/V fragments read directly from global (L2-resident; 17 WGs share K/V per
// (b,h)). Per-wave P round-trip through 2KB LDS. Online softmax in registers.
// ---------------------------------------------------------------------------
__global__ __launch_bounds__(256) void attn_mfma(const u16* __restrict__ qh,
                                                 const u16* __restrict__ kh,
                                                 const u16* __restrict__ vt,
                                                 u16* __restrict__ outb) {
  __shared__ __align__(16) char sm[8192];  // P: 4 waves x 2KB
  const int tid = threadIdx.x;
  const int lid = tid & 63, w = tid >> 6;
  const int l15 = lid & 15, lg = lid >> 4;
  const int qblk = blockIdx.x;
  const int h = blockIdx.y, b = blockIdx.z;
  const int bh = b * HH + h;
  const int q0w = qblk * 64 + w * 16;
  const int PB = w * 2048;
  const u16* kbase = kh + (size_t)bh * SS * 64;
  const u16* vbase = vt + (size_t)bh * DH * SSP;

  bf8 qf[2];
  {
    int row = q0w + l15; if (row >= SS) row = SS - 1;
    const u16* qp = qh + ((size_t)bh * SS + row) * 64;
#pragma unroll
    for (int kf = 0; kf < 2; ++kf)
      qf[kf] = *reinterpret_cast<const bf8*>(qp + kf * 32 + lg * 8);
  }

  float m_r[4], l_r[4];
  f32x4 accO[3] = {};
#pragma unroll
  for (int r = 0; r < 4; ++r) { m_r[r] = -1e30f; l_r[r] = 0.f; }

  const int nch = (qblk < 8) ? 9 : 17;
  for (int c = 0; c < nch; ++c) {
    const int j0 = c * 64;
    // QK^T: fragments straight from global
    f32x4 sv[4];
#pragma unroll
    for (int jt = 0; jt < 4; ++jt) {
      int jrow = j0 + jt * 16 + l15; if (jrow >= SS) jrow = SS - 1;
      const u16* kp = kbase + (size_t)jrow * 64 + lg * 8;
      bf8 kb0 = *reinterpret_cast<const bf8*>(kp);
      bf8 kb1 = *reinterpret_cast<const bf8*>(kp + 32);
      f32x4 z = {};
      z = __builtin_amdgcn_mfma_f32_16x16x32_bf16(qf[0], kb0, z, 0, 0, 0);
      z = __builtin_amdgcn_mfma_f32_16x16x32_bf16(qf[1], kb1, z, 0, 0, 0);
      sv[jt] = z;
    }

    const bool domask = (c == 8) | (c == 16) | ((q0w < NM1) & (c > 8));
    float pv[4][4], alpha[4];
#pragma unroll
    for (int r = 0; r < 4; ++r) {
      float mx = -1e30f;
      if (domask) {
        int qrow = q0w + lg * 4 + r;
#pragma unroll
        for (int jt = 0; jt < 4; ++jt) {
          int jcol = j0 + jt * 16 + l15;
          float s = sv[jt][r];
          if (jcol >= SS || (qrow < NM1 && jcol >= NM1)) s = -1e30f;
          sv[jt][r] = s;
          mx = fmaxf(mx, s);
        }
      } else {
#pragma unroll
        for (int jt = 0; jt < 4; ++jt) mx = fmaxf(mx, sv[jt][r]);
      }
      mx = fmaxf(mx, __shfl_xor(mx, 1));
      mx = fmaxf(mx, __shfl_xor(mx, 2));
      mx = fmaxf(mx, __shfl_xor(mx, 4));
      mx = fmaxf(mx, __shfl_xor(mx, 8));
      float mn = fmaxf(m_r[r], mx);
      alpha[r] = __expf(m_r[r] - mn);
      float ps = 0.f;
#pragma unroll
      for (int jt = 0; jt < 4; ++jt) {
        float p = __expf(sv[jt][r] - mn);
        pv[jt][r] = p;
        ps += p;
      }
      ps += __shfl_xor(ps, 1);
      ps += __shfl_xor(ps, 2);
      ps += __shfl_xor(ps, 4);
      ps += __shfl_xor(ps, 8);
      l_r[r] = l_r[r] * alpha[r] + ps;
      m_r[r] = mn;
    }
#pragma unroll
    for (int dt = 0; dt < 3; ++dt)
#pragma unroll
      for (int r = 0; r < 4; ++r) accO[dt][r] *= alpha[r];

    // P -> per-wave LDS (swizzled) -> A-fragments
#pragma unroll
    for (int jt = 0; jt < 4; ++jt)
#pragma unroll
      for (int r = 0; r < 4; ++r) {
        int qp = lg * 4 + r;
        int off = ((qp << 7) + ((jt * 16 + l15) << 1)) ^ ((qp & 7) << 4);
        *reinterpret_cast<u16*>(sm + PB + off) = f2bf(pv[jt][r]);
      }
    bf8 pa[2];
#pragma unroll
    for (int jc = 0; jc < 2; ++jc) {
      int off = ((l15 << 7) + (jc << 6) + (lg << 4)) ^ ((l15 & 7) << 4);
      pa[jc] = *reinterpret_cast<const bf8*>(sm + PB + off);
    }
    // PV: V fragments straight from global (vt pad cols are zeroed)
#pragma unroll
    for (int dt = 0; dt < 3; ++dt) {
      const u16* vp = vbase + (size_t)(dt * 16 + l15) * SSP + j0 + lg * 8;
#pragma unroll
      for (int jc = 0; jc < 2; ++jc) {
        bf8 vb = *reinterpret_cast<const bf8*>(vp + jc * 32);
        accO[dt] = __builtin_amdgcn_mfma_f32_16x16x32_bf16(pa[jc], vb, accO[dt], 0, 0, 0);
      }
    }
  }

#pragma unroll
  for (int r = 0; r < 4; ++r) {
    int q = q0w + lg * 4 + r;
    if (q >= SS) continue;
    float inv = 1.0f / l_r[r];
#pragma unroll
    for (int dt = 0; dt < 3; ++dt) {
      int d = dt * 16 + l15;
      outb[((size_t)(b * SS + q)) * DD + h * DH + d] = f2bf(accO[dt][r] * inv);
    }
  }
}

// ---------------------------------------------------------------------------
// out = LayerNorm(a + r) * g + be, fp32 + bf16 mirror.
// ---------------------------------------------------------------------------
__global__ __launch_bounds__(128) void add_ln(const float* __restrict__ a,
                                              const float* __restrict__ r,
                                              const float* __restrict__ g,
                                              const float* __restrict__ be,
                                              float* __restrict__ out,
                                              u16* __restrict__ outb) {
  __shared__ float p1[2], p2[2];
  const int row = blockIdx.x;
  const int t = threadIdx.x;
  const size_t base = (size_t)row * DD;
  float x0 = a[base + t] + r[base + t];
  float x1 = a[base + t + 128] + r[base + t + 128];
  float x2 = a[base + t + 256] + r[base + t + 256];
  float s = x0 + x1 + x2;
#pragma unroll
  for (int off = 32; off; off >>= 1) s += __shfl_xor(s, off);
  if ((t & 63) == 0) p1[t >> 6] = s;
  __syncthreads();
  float mean = (p1[0] + p1[1]) * (1.0f / 384.0f);
  float d0 = x0 - mean, d1 = x1 - mean, d2 = x2 - mean;
  float vsum = d0 * d0 + d1 * d1 + d2 * d2;
#pragma unroll
  for (int off = 32; off; off >>= 1) vsum += __shfl_xor(vsum, off);
  if ((t & 63) == 0) p2[t >> 6] = vsum;
  __syncthreads();
  float var = (p2[0] + p2[1]) * (1.0f / 384.0f);
  float rs = rsqrtf(var + 1e-5f);
  float o0 = d0 * rs * g[t]       + be[t];
  float o1 = d1 * rs * g[t + 128] + be[t + 128];
  float o2 = d2 * rs * g[t + 256] + be[t + 256];
  out[base + t] = o0;        outb[base + t] = f2bf(o0);
  out[base + t + 128] = o1;  outb[base + t + 128] = f2bf(o1);
  out[base + t + 256] = o2;  outb[base + t + 256] = f2bf(o2);
}

__global__ void copy_out(const float* __restrict__ src, float* __restrict__ out) {
  int idx = blockIdx.x * 256 + threadIdx.x;
  if (idx >= BB * TT * DD) return;
  int d = idx % DD;
  int bt = idx / DD;
  int t = bt % TT;
  int b = bt / TT;
  out[idx] = src[((size_t)b * SS + (SS - TT) + t) * DD + d];
}

// ---------------------------------------------------------------------------
extern "C" void kernel_launch(void* const* d_in, const int* in_sizes, int n_in,
                              void* d_out, int out_size, void* d_ws, size_t ws_size,
                              hipStream_t stream) {
  const float* hand_t    = (const float*)d_in[0];
  const float* head_t    = (const float*)d_in[1];
  const float* hand_m1   = (const float*)d_in[2];
  const float* head_m1   = (const float*)d_in[3];
  const float* c_hand_t  = (const float*)d_in[4];
  const float* c_head_t  = (const float*)d_in[5];
  const float* c_hand_m1 = (const float*)d_in[6];
  const float* c_head_m1 = (const float*)d_in[7];
  const float* state_t   = (const float*)d_in[8];
  const float* state_m1  = (const float*)d_in[9];
  const float* tr_t      = (const float*)d_in[10];
  const float* tr_m1     = (const float*)d_in[11];
  const float* tok_m1    = (const float*)d_in[12];
  const float* tok_t     = (const float*)d_in[13];
  const float* Wq = (const float*)d_in[14];
  const float* bq = (const float*)d_in[15];
  const float* Wk = (const float*)d_in[16];
  const float* bk = (const float*)d_in[17];
  const float* Wv = (const float*)d_in[18];
  const float* bv = (const float*)d_in[19];
  const float* Wo = (const float*)d_in[20];
  const float* bo = (const float*)d_in[21];
  const float* W1 = (const float*)d_in[22];
  const float* b1 = (const float*)d_in[23];
  const float* W2 = (const float*)d_in[24];
  const float* b2 = (const float*)d_in[25];
  const float* g1 = (const float*)d_in[26];
  const float* be1 = (const float*)d_in[27];
  const float* g2 = (const float*)d_in[28];
  const float* be2 = (const float*)d_in[29];

  const size_t SRC_N = (size_t)BB * SS * DD;       // 3,176,448
  float* src    = (float*)d_ws;
  float* src2   = src + SRC_N;
  float* bufB   = src2 + SRC_N;
  float* coords = bufB + SRC_N;                    // 24,816
  float* bqkv   = coords + (size_t)BB * SS * 3;    // L*1152 = 6,912
  u16* srcb  = (u16*)(bqkv + (size_t)LL * NQKV);
  u16* src2b = srcb + SRC_N;
  u16* attnb = src2b + SRC_N;
  u16* qh  = attnb + SRC_N;
  const size_t QH_N = (size_t)BB * HH * SS * 64;   // 4,233,216
  u16* khb = qh + QH_N;
  u16* vtb = khb + QH_N;                           // 64*48*1088 = 3,342,336
  u16* hbf = vtb + (size_t)64 * DH * SSP;          // 12,705,792
  u16* wqkv_b = hbf + (size_t)MROWS * FFD;         // L*1152*384 = 2,654,208
  const size_t WD = (size_t)LL * DD * DD;          // 884,736
  const size_t WF = (size_t)LL * FFD * DD;         // 3,538,944
  u16* wo_bf = wqkv_b + (size_t)LL * NQKV * 384;
  u16* w1_bf = wo_bf + WD;
  u16* w2_bf = w1_bf + WF;

  const int M = MROWS;
  dim3 blk(256);

  build_src<<<(BB * SS * DD + 255) / 256, blk, 0, stream>>>(
      hand_t, head_t, hand_m1, head_m1, state_t, state_m1, tok_m1, tok_t, src, srcb);
  build_coords<<<(BB * SS * 3 + 255) / 256, blk, 0, stream>>>(
      c_hand_t, c_head_t, c_hand_m1, c_head_m1, tr_t, tr_m1, coords);
  pack_qkv<<<(LL * NQKV * 96 + 255) / 256, blk, 0, stream>>>(Wq, Wk, Wv, wqkv_b);
  pack_bqkv<<<(LL * NQKV + 255) / 256, blk, 0, stream>>>(bq, bk, bv, bqkv);
  cvt_bf<<<(int)(WD / 4 + 255) / 256, blk, 0, stream>>>(Wo, wo_bf, (int)(WD / 4));
  cvt_bf<<<(int)(WF / 4 + 255) / 256, blk, 0, stream>>>(W1, w1_bf, (int)(WF / 4));
  cvt_bf<<<(int)(WF / 4 + 255) / 256, blk, 0, stream>>>(W2, w2_bf, (int)(WF / 4));
  pad_vt<<<(64 * DH * (SSP - SS) + 255) / 256, blk, 0, stream>>>(vtb);

  dim3 gq(DD / 64, (M + 127) / 128);       // (6, 65)
  dim3 gqkv(NQKV / 64, (M + 127) / 128);   // (18, 65)
  dim3 gf1(FFD / 64, (M + 127) / 128);     // (24, 65)
  dim3 gattn((SS + 63) / 64, HH, BB);      // (17, 8, 8)

  for (int l = 0; l < LL; ++l) {
    const u16* Wqkv_l = wqkv_b + (size_t)l * NQKV * 384;
    const u16* Wo_l = wo_bf + (size_t)l * DD * DD;
    const u16* W1_l = w1_bf + (size_t)l * FFD * DD;
    const u16* W2_l = w2_bf + (size_t)l * DD * FFD;

    gemm_as<0, 2><<<gqkv, blk, 0, stream>>>(srcb, Wqkv_l, bqkv + l * NQKV,
                                            nullptr, qh, khb, vtb, M, NQKV, DD);
    rope_bf<<<(BB * HH * SS * 32 + 255) / 256, blk, 0, stream>>>(qh, khb, coords);
    attn_mfma<<<gattn, blk, 0, stream>>>(qh, khb, vtb, attnb);
    gemm_as<0, 0><<<gq, blk, 0, stream>>>(attnb, Wo_l, bo + l * DD,
                                          bufB, nullptr, nullptr, nullptr, M, DD, DD);
    add_ln<<<M, 128, 0, stream>>>(src, bufB, g1 + l * DD, be1 + l * DD, src2, src2b);
    gemm_as<1, 1><<<gf1, blk, 0, stream>>>(src2b, W1_l, b1 + l * FFD,
                                           nullptr, hbf, nullptr, nullptr, M, FFD, DD);
    gemm_as<0, 0><<<gq, blk, 0, stream>>>(hbf, W2_l, b2 + l * DD,
                                          bufB, nullptr, nullptr, nullptr, M, DD, FFD);
    add_ln<<<M, 128, 0, stream>>>(src2, bufB, g2 + l * DD, be2 + l * DD, src, srcb);
  }
  copy_out<<<(BB * TT * DD + 255) / 256, blk, 0, stream>>>(src, (float*)d_out);
}

// Round 4
// 1324.688 us; speedup vs baseline: 6.7924x; 1.2390x over previous
//
#include <hip/hip_runtime.h>
#include <hip/hip_bf16.h>
#include <math.h>

#define BB 8
#define NN 256
#define DD 384
#define LL 6
#define HH 8
#define FFD 1536
#define TT 4
#define DH 48
#define NM1 517      // T + 1 + 2N
#define SS 1034      // 2 * NM1
#define SSP 1088     // padded key stride for vt (17*64)
#define MROWS (BB*SS)
#define NQKV 1152
#define QSCALE 0.14433756729740643f

typedef unsigned short u16;
typedef short bf8 __attribute__((ext_vector_type(8)));
typedef float f32x4 __attribute__((ext_vector_type(4)));

__device__ __forceinline__ u16 f2bf(float f) {
  __hip_bfloat16 h = __float2bfloat16(f);
  return *reinterpret_cast<u16*>(&h);
}
__device__ __forceinline__ float bf2f(u16 u) {
  __hip_bfloat16 h;
  *reinterpret_cast<u16*>(&h) = u;
  return __bfloat162float(h);
}
// async global->LDS, 16B per lane; lds dest wave-uniform (HW adds lane*16)
__device__ __forceinline__ void async16(void* lds, const void* g) {
  __builtin_amdgcn_global_load_lds(
      (const __attribute__((address_space(1))) unsigned int*)g,
      (__attribute__((address_space(3))) unsigned int*)lds, 16, 0, 0);
}

// ---------------------------------------------------------------------------
// src assembly: fp32 residual + bf16 mirror.
// ---------------------------------------------------------------------------
__global__ void build_src(const float* __restrict__ hand_t, const float* __restrict__ head_t,
                          const float* __restrict__ hand_m1, const float* __restrict__ head_m1,
                          const float* __restrict__ state_t, const float* __restrict__ state_m1,
                          const float* __restrict__ tok_m1, const float* __restrict__ tok_t,
                          float* __restrict__ src, u16* __restrict__ srcb) {
  int idx = blockIdx.x * 256 + threadIdx.x;
  if (idx >= BB * SS * DD) return;
  int d = idx % DD;
  int bs = idx / DD;
  int s = bs % SS;
  int b = bs / SS;
  float val;
  if (s == 0)               val = state_m1[b * DD + d];
  else if (s <= NN)         val = hand_m1[((size_t)(b * NN + (s - 1))) * DD + d];
  else if (s <= 2 * NN)     val = head_m1[((size_t)(b * NN + (s - 1 - NN))) * DD + d];
  else if (s <= 2 * NN + TT) val = tok_m1[(s - (2 * NN + 1)) * DD + d];
  else if (s == NM1)        val = state_t[b * DD + d];
  else if (s <= NM1 + NN)   val = hand_t[((size_t)(b * NN + (s - NM1 - 1))) * DD + d];
  else if (s <= NM1 + 2 * NN) val = head_t[((size_t)(b * NN + (s - NM1 - 1 - NN))) * DD + d];
  else                      val = tok_t[(s - (NM1 + 2 * NN + 1)) * DD + d];
  src[idx] = val;
  srcb[idx] = f2bf(val);
}

__global__ void build_coords(const float* __restrict__ c_hand_t, const float* __restrict__ c_head_t,
                             const float* __restrict__ c_hand_m1, const float* __restrict__ c_head_m1,
                             const float* __restrict__ tr_t, const float* __restrict__ tr_m1,
                             float* __restrict__ coords) {
  int idx = blockIdx.x * 256 + threadIdx.x;
  if (idx >= BB * SS * 3) return;
  int a = idx % 3;
  int bs = idx / 3;
  int s = bs % SS;
  int b = bs / SS;
  float val;
  if (s == 0)               val = tr_m1[b * 3 + a];
  else if (s <= NN)         val = c_hand_m1[(b * NN + (s - 1)) * 3 + a];
  else if (s <= 2 * NN)     val = c_head_m1[(b * NN + (s - 1 - NN)) * 3 + a];
  else if (s <= 2 * NN + TT) val = tr_m1[b * 3 + a];
  else if (s == NM1)        val = tr_t[b * 3 + a];
  else if (s <= NM1 + NN)   val = c_hand_t[(b * NN + (s - NM1 - 1)) * 3 + a];
  else if (s <= NM1 + 2 * NN) val = c_head_t[(b * NN + (s - NM1 - 1 - NN)) * 3 + a];
  else                      val = tr_t[b * 3 + a];
  coords[idx] = val;
}

// cos/sin table: trig[(b*SS+s)*24 + axis*8 + i] = {cos, sin}(coords*inv_freq)
__global__ void build_trig(const float* __restrict__ coords, float2* __restrict__ trig) {
  int idx = blockIdx.x * 256 + threadIdx.x;
  if (idx >= BB * SS * 24) return;
  int i = idx & 7;
  int axis = (idx >> 3) % 3;
  int bs = idx / 24;
  float cv = coords[bs * 3 + axis];
  float inv = expf(-(float)i * 1.1512925464970229f);  // 10000^(-i/8)
  float ang = cv * inv;
  trig[idx] = make_float2(cosf(ang), sinf(ang));
}

// ---------------------------------------------------------------------------
// weight conversion / packing
// ---------------------------------------------------------------------------
__global__ void cvt_bf(const float* __restrict__ in, u16* __restrict__ out, int n4) {
  int idx = blockIdx.x * 256 + threadIdx.x;
  if (idx >= n4) return;
  float4 v = reinterpret_cast<const float4*>(in)[idx];
  short4 o;
  o.x = (short)f2bf(v.x); o.y = (short)f2bf(v.y);
  o.z = (short)f2bf(v.z); o.w = (short)f2bf(v.w);
  reinterpret_cast<short4*>(out)[idx] = o;
}

__global__ void pack_qkv(const float* __restrict__ Wq, const float* __restrict__ Wk,
                         const float* __restrict__ Wv, u16* __restrict__ wqkv) {
  int idx = blockIdx.x * 256 + threadIdx.x;
  const int TOTAL = LL * NQKV * 96;
  if (idx >= TOTAL) return;
  int k4 = idx % 96;
  int n = (idx / 96) % NQKV;
  int l = idx / (96 * NQKV);
  int sel = n / 384, nn = n - sel * 384;
  const float* W = (sel == 0) ? Wq : ((sel == 1) ? Wk : Wv);
  float4 v = *reinterpret_cast<const float4*>(W + ((size_t)l * 384 + nn) * 384 + k4 * 4);
  short4 o;
  o.x = (short)f2bf(v.x); o.y = (short)f2bf(v.y);
  o.z = (short)f2bf(v.z); o.w = (short)f2bf(v.w);
  *reinterpret_cast<short4*>(wqkv + ((size_t)(l * NQKV + n) * 384 + k4 * 4)) = o;
}

__global__ void pack_bqkv(const float* __restrict__ bq, const float* __restrict__ bk,
                          const float* __restrict__ bv, float* __restrict__ bqkv) {
  int idx = blockIdx.x * 256 + threadIdx.x;
  if (idx >= LL * NQKV) return;
  int n = idx % NQKV, l = idx / NQKV;
  int sel = n / 384, nn = n - sel * 384;
  const float* Bp = (sel == 0) ? bq : ((sel == 1) ? bk : bv);
  bqkv[idx] = Bp[l * 384 + nn];
}

// zero the padded key columns [SS, SSP) of vt
__global__ void pad_vt(u16* __restrict__ vt) {
  int idx = blockIdx.x * 256 + threadIdx.x;
  const int PADW = SSP - SS;
  if (idx >= 64 * DH * PADW) return;
  int c = idx % PADW;
  int rd = idx / PADW;
  vt[(size_t)rd * SSP + SS + c] = 0;
}

// zero the d=48..63 pad of qh/kh once (GEMM epilogue writes only d<48)
__global__ void pad_qk(u16* __restrict__ qh, u16* __restrict__ kh) {
  int idx = blockIdx.x * 256 + threadIdx.x;
  if (idx >= 64 * SS * 16) return;
  int c = idx & 15;
  int row = idx >> 4;
  qh[(size_t)row * 64 + 48 + c] = 0;
  kh[(size_t)row * 64 + 48 + c] = 0;
}

// ---------------------------------------------------------------------------
// MFMA GEMM, bf16 in, async global->LDS staging.
//   C[m,n] = sum_k A[m,k]*W[n,k] + bias[n]
//   EPI: 0 none, 1 exact GELU.
//   OUT: 0 fp32 row-major, 1 bf16 row-major, 2 fused-QKV routing WITH RoPE
//        (rotation partner via __shfl_xor(v,8); cos/sin from trig table).
// Tile 128x64, BK=64, 4 waves (2x2).
// ---------------------------------------------------------------------------
template <int EPI, int OUT>
__global__ __launch_bounds__(256) void gemm_as(
    const u16* __restrict__ Ab, const u16* __restrict__ Wb,
    const float* __restrict__ bias, const float2* __restrict__ trig,
    float* __restrict__ Cf, u16* __restrict__ Cb,
    u16* __restrict__ Ck, u16* __restrict__ Cv,
    int M, int N, int K) {
  __shared__ __align__(16) char sm[24576];  // A 16KB @0, B 8KB @16384
  const int tid = threadIdx.x;
  const int bm = blockIdx.y * 128, bn = blockIdx.x * 64;
  const int lid = tid & 63, w = tid >> 6;
  const int wm = w >> 1, wn = w & 1;
  const int l15 = lid & 15, lg = lid >> 4;
  const int lr = lid >> 3, lu = lid & 7;
  const int swz = lu ^ lr;
  f32x4 acc[4][2] = {};

  for (int k0 = 0; k0 < K; k0 += 64) {
    __syncthreads();
#pragma unroll
    for (int q = 0; q < 4; ++q) {
      int row = w * 32 + q * 8 + lr;
      int grow = bm + row; if (grow >= M) grow = M - 1;
      async16(sm + w * 4096 + q * 1024, Ab + (size_t)grow * K + k0 + (swz << 3));
    }
#pragma unroll
    for (int q = 0; q < 2; ++q) {
      int row = w * 16 + q * 8 + lr;
      async16(sm + 16384 + w * 2048 + q * 1024, Wb + (size_t)(bn + row) * K + k0 + (swz << 3));
    }
    __syncthreads();
    bf8 a[2][4], bfr[2][2];
#pragma unroll
    for (int kf = 0; kf < 2; ++kf) {
#pragma unroll
      for (int mt = 0; mt < 4; ++mt) {
        int row = wm * 64 + mt * 16 + l15;
        int off = ((row << 7) + (kf << 6) + (lg << 4)) ^ ((row & 7) << 4);
        a[kf][mt] = *reinterpret_cast<const bf8*>(sm + off);
      }
#pragma unroll
      for (int nt = 0; nt < 2; ++nt) {
        int row = wn * 32 + nt * 16 + l15;
        int off = 16384 + (((row << 7) + (kf << 6) + (lg << 4)) ^ ((row & 7) << 4));
        bfr[kf][nt] = *reinterpret_cast<const bf8*>(sm + off);
      }
    }
#pragma unroll
    for (int kf = 0; kf < 2; ++kf)
#pragma unroll
      for (int mt = 0; mt < 4; ++mt)
#pragma unroll
        for (int nt = 0; nt < 2; ++nt)
          acc[mt][nt] = __builtin_amdgcn_mfma_f32_16x16x32_bf16(a[kf][mt], bfr[kf][nt], acc[mt][nt], 0, 0, 0);
  }

#pragma unroll
  for (int nt = 0; nt < 2; ++nt) {
    const int n = bn + wn * 32 + nt * 16 + l15;
    const float bsv = bias[n];
#pragma unroll
    for (int mt = 0; mt < 4; ++mt) {
      const int m0 = bm + wm * 64 + mt * 16 + lg * 4;
      if (OUT != 2) {
#pragma unroll
        for (int r = 0; r < 4; ++r) {
          int m = m0 + r;
          if (m >= M) continue;
          float v = acc[mt][nt][r] + bsv;
          if (EPI == 1) v = 0.5f * v * (1.0f + erff(v * 0.70710678118654752f));
          if (OUT == 0) Cf[(size_t)m * N + n] = v;
          else          Cb[(size_t)m * N + n] = f2bf(v);
        }
      } else {
        const int sel = n / 384, nn = n - sel * 384;
        const int hdiv = nn / DH, hrem = nn - hdiv * DH;
        const int axis = hrem >> 4, ii = l15 & 7;
        const bool lo = (l15 & 8) == 0;
#pragma unroll
        for (int r = 0; r < 4; ++r) {
          int m = m0 + r;
          int mc = (m < M) ? m : (M - 1);
          float v = acc[mt][nt][r] + bsv;
          float p = __shfl_xor(v, 8);  // rotation partner (d +/- 8), all lanes
          int bI = mc / SS, s = mc - bI * SS;
          float outv;
          if (sel < 2) {
            float2 t = trig[(size_t)(bI * SS + s) * 24 + axis * 8 + ii];
            outv = lo ? (v * t.x - p * t.y) : (p * t.y + v * t.x);
            if (sel == 0) outv *= QSCALE;
          } else {
            outv = v;
          }
          if (m < M) {
            int bh = bI * HH + hdiv;
            if (sel == 0)      Cb[((size_t)bh * SS + s) * 64 + hrem] = f2bf(outv);
            else if (sel == 1) Ck[((size_t)bh * SS + s) * 64 + hrem] = f2bf(outv);
            else               Cv[((size_t)bh * DH + hrem) * SSP + s] = f2bf(outv);
          }
        }
      }
    }
  }
}

// ---------------------------------------------------------------------------
// Flash attention v4: 64 queries/WG (4 waves), K/V chunks double-buffered in
// LDS via async global_load_lds (linear dest + pre-swizzled source), ONE
// barrier per chunk (staging of c+1 issued before compute of c; the barrier's
// implicit vmcnt drain lands after compute hides the latency).
// ---------------------------------------------------------------------------
__global__ __launch_bounds__(256) void attn_mfma(const u16* __restrict__ qh,
                                                 const u16* __restrict__ kh,
                                                 const u16* __restrict__ vt,
                                                 u16* __restrict__ outb) {
  // buf b: K 8KB @ b*14336, Vt 6KB @ b*14336+8192 ; P @ 28672 + w*2048
  __shared__ __align__(16) char sm[36864];
  const int tid = threadIdx.x;
  const int lid = tid & 63, w = tid >> 6;
  const int l15 = lid & 15, lg = lid >> 4;
  const int lr = lid >> 3, lu = lid & 7;
  const int swz8 = (lu ^ lr) << 3;
  const int qblk = blockIdx.x;
  const int h = blockIdx.y, b = blockIdx.z;
  const int bh = b * HH + h;
  const int q0w = qblk * 64 + w * 16;
  const int PB = 28672 + w * 2048;
  const u16* kbase = kh + (size_t)bh * SS * 64;
  const u16* vbase = vt + (size_t)bh * DH * SSP;

  bf8 qf[2];
  {
    int row = q0w + l15; if (row >= SS) row = SS - 1;
    const u16* qp = qh + ((size_t)bh * SS + row) * 64;
    qf[0] = *reinterpret_cast<const bf8*>(qp + lg * 8);
    qf[1] = *reinterpret_cast<const bf8*>(qp + 32 + lg * 8);
  }

  float m_r[4], l_r[4];
  f32x4 accO[3] = {};
#pragma unroll
  for (int r = 0; r < 4; ++r) { m_r[r] = -1e30f; l_r[r] = 0.f; }

  const int nch = (qblk < 8) ? 9 : 17;

  auto stage = [&](int bsel, int c) {
    const int j0 = c * 64;
    char* kb = sm + bsel * 14336;
    char* vb = kb + 8192;
#pragma unroll
    for (int qq = 0; qq < 2; ++qq) {
      int is = w * 2 + qq;
      int jrow = j0 + is * 8 + lr; if (jrow >= SS) jrow = SS - 1;
      async16(kb + is * 1024, kbase + (size_t)jrow * 64 + swz8);
    }
    async16(vb + w * 1024, vbase + (size_t)(w * 8 + lr) * SSP + j0 + swz8);
    if (w < 2)
      async16(vb + (4 + w) * 1024, vbase + (size_t)((4 + w) * 8 + lr) * SSP + j0 + swz8);
  };

  stage(0, 0);
  __syncthreads();
  int bsel = 0;

  for (int c = 0; c < nch; ++c) {
    if (c + 1 < nch) stage(bsel ^ 1, c + 1);
    const int j0 = c * 64;
    const char* kb = sm + bsel * 14336;
    const char* vb = kb + 8192;

    // QK^T from LDS
    f32x4 sv[4];
#pragma unroll
    for (int jt = 0; jt < 4; ++jt) {
      int row = jt * 16 + l15;
      int off0 = ((row << 7) + (lg << 4)) ^ ((row & 7) << 4);
      int off1 = ((row << 7) + 64 + (lg << 4)) ^ ((row & 7) << 4);
      bf8 kb0 = *reinterpret_cast<const bf8*>(kb + off0);
      bf8 kb1 = *reinterpret_cast<const bf8*>(kb + off1);
      f32x4 z = {};
      z = __builtin_amdgcn_mfma_f32_16x16x32_bf16(qf[0], kb0, z, 0, 0, 0);
      z = __builtin_amdgcn_mfma_f32_16x16x32_bf16(qf[1], kb1, z, 0, 0, 0);
      sv[jt] = z;
    }

    const bool domask = (c == 16) | ((q0w < NM1) & (c >= 8));
    float pv[4][4], alpha[4];
#pragma unroll
    for (int r = 0; r < 4; ++r) {
      float mx = -1e30f;
      if (domask) {
        int qrow = q0w + lg * 4 + r;
#pragma unroll
        for (int jt = 0; jt < 4; ++jt) {
          int jcol = j0 + jt * 16 + l15;
          float s = sv[jt][r];
          if (jcol >= SS || (qrow < NM1 && jcol >= NM1)) s = -1e30f;
          sv[jt][r] = s;
          mx = fmaxf(mx, s);
        }
      } else {
#pragma unroll
        for (int jt = 0; jt < 4; ++jt) mx = fmaxf(mx, sv[jt][r]);
      }
      mx = fmaxf(mx, __shfl_xor(mx, 1));
      mx = fmaxf(mx, __shfl_xor(mx, 2));
      mx = fmaxf(mx, __shfl_xor(mx, 4));
      mx = fmaxf(mx, __shfl_xor(mx, 8));
      float mn = fmaxf(m_r[r], mx);
      alpha[r] = __expf(m_r[r] - mn);
      float ps = 0.f;
#pragma unroll
      for (int jt = 0; jt < 4; ++jt) {
        float p = __expf(sv[jt][r] - mn);
        pv[jt][r] = p;
        ps += p;
      }
      ps += __shfl_xor(ps, 1);
      ps += __shfl_xor(ps, 2);
      ps += __shfl_xor(ps, 4);
      ps += __shfl_xor(ps, 8);
      l_r[r] = l_r[r] * alpha[r] + ps;
      m_r[r] = mn;
    }
#pragma unroll
    for (int dt = 0; dt < 3; ++dt)
#pragma unroll
      for (int r = 0; r < 4; ++r) accO[dt][r] *= alpha[r];

    // P -> per-wave LDS (swizzled) -> A-fragments
#pragma unroll
    for (int jt = 0; jt < 4; ++jt)
#pragma unroll
      for (int r = 0; r < 4; ++r) {
        int qp = lg * 4 + r;
        int off = ((qp << 7) + ((jt * 16 + l15) << 1)) ^ ((qp & 7) << 4);
        *reinterpret_cast<u16*>(sm + PB + off) = f2bf(pv[jt][r]);
      }
    bf8 pa[2];
#pragma unroll
    for (int jc = 0; jc < 2; ++jc) {
      int off = ((l15 << 7) + (jc << 6) + (lg << 4)) ^ ((l15 & 7) << 4);
      pa[jc] = *reinterpret_cast<const bf8*>(sm + PB + off);
    }
    // PV from LDS Vt tile
#pragma unroll
    for (int dt = 0; dt < 3; ++dt) {
      int row = dt * 16 + l15;
#pragma unroll
      for (int jc = 0; jc < 2; ++jc) {
        int off = ((row << 7) + (jc << 6) + (lg << 4)) ^ ((row & 7) << 4);
        bf8 vb8 = *reinterpret_cast<const bf8*>(vb + off);
        accO[dt] = __builtin_amdgcn_mfma_f32_16x16x32_bf16(pa[jc], vb8, accO[dt], 0, 0, 0);
      }
    }
    __syncthreads();  // drains vmcnt (c+1 staged) + frees buf for c+2
    bsel ^= 1;
  }

#pragma unroll
  for (int r = 0; r < 4; ++r) {
    int q = q0w + lg * 4 + r;
    if (q >= SS) continue;
    float inv = 1.0f / l_r[r];
#pragma unroll
    for (int dt = 0; dt < 3; ++dt) {
      int d = dt * 16 + l15;
      outb[((size_t)(b * SS + q)) * DD + h * DH + d] = f2bf(accO[dt][r] * inv);
    }
  }
}

// ---------------------------------------------------------------------------
// out = LayerNorm(a + r) * g + be, fp32 + bf16 mirror.
// ---------------------------------------------------------------------------
__global__ __launch_bounds__(128) void add_ln(const float* __restrict__ a,
                                              const float* __restrict__ r,
                                              const float* __restrict__ g,
                                              const float* __restrict__ be,
                                              float* __restrict__ out,
                                              u16* __restrict__ outb) {
  __shared__ float p1[2], p2[2];
  const int row = blockIdx.x;
  const int t = threadIdx.x;
  const size_t base = (size_t)row * DD;
  float x0 = a[base + t] + r[base + t];
  float x1 = a[base + t + 128] + r[base + t + 128];
  float x2 = a[base + t + 256] + r[base + t + 256];
  float s = x0 + x1 + x2;
#pragma unroll
  for (int off = 32; off; off >>= 1) s += __shfl_xor(s, off);
  if ((t & 63) == 0) p1[t >> 6] = s;
  __syncthreads();
  float mean = (p1[0] + p1[1]) * (1.0f / 384.0f);
  float d0 = x0 - mean, d1 = x1 - mean, d2 = x2 - mean;
  float vsum = d0 * d0 + d1 * d1 + d2 * d2;
#pragma unroll
  for (int off = 32; off; off >>= 1) vsum += __shfl_xor(vsum, off);
  if ((t & 63) == 0) p2[t >> 6] = vsum;
  __syncthreads();
  float var = (p2[0] + p2[1]) * (1.0f / 384.0f);
  float rs = rsqrtf(var + 1e-5f);
  float o0 = d0 * rs * g[t]       + be[t];
  float o1 = d1 * rs * g[t + 128] + be[t + 128];
  float o2 = d2 * rs * g[t + 256] + be[t + 256];
  out[base + t] = o0;        outb[base + t] = f2bf(o0);
  out[base + t + 128] = o1;  outb[base + t + 128] = f2bf(o1);
  out[base + t + 256] = o2;  outb[base + t + 256] = f2bf(o2);
}

__global__ void copy_out(const float* __restrict__ src, float* __restrict__ out) {
  int idx = blockIdx.x * 256 + threadIdx.x;
  if (idx >= BB * TT * DD) return;
  int d = idx % DD;
  int bt = idx / DD;
  int t = bt % TT;
  int b = bt / TT;
  out[idx] = src[((size_t)b * SS + (SS - TT) + t) * DD + d];
}

// ---------------------------------------------------------------------------
extern "C" void kernel_launch(void* const* d_in, const int* in_sizes, int n_in,
                              void* d_out, int out_size, void* d_ws, size_t ws_size,
                              hipStream_t stream) {
  const float* hand_t    = (const float*)d_in[0];
  const float* head_t    = (const float*)d_in[1];
  const float* hand_m1   = (const float*)d_in[2];
  const float* head_m1   = (const float*)d_in[3];
  const float* c_hand_t  = (const float*)d_in[4];
  const float* c_head_t  = (const float*)d_in[5];
  const float* c_hand_m1 = (const float*)d_in[6];
  const float* c_head_m1 = (const float*)d_in[7];
  const float* state_t   = (const float*)d_in[8];
  const float* state_m1  = (const float*)d_in[9];
  const float* tr_t      = (const float*)d_in[10];
  const float* tr_m1     = (const float*)d_in[11];
  const float* tok_m1    = (const float*)d_in[12];
  const float* tok_t     = (const float*)d_in[13];
  const float* Wq = (const float*)d_in[14];
  const float* bq = (const float*)d_in[15];
  const float* Wk = (const float*)d_in[16];
  const float* bk = (const float*)d_in[17];
  const float* Wv = (const float*)d_in[18];
  const float* bv = (const float*)d_in[19];
  const float* Wo = (const float*)d_in[20];
  const float* bo = (const float*)d_in[21];
  const float* W1 = (const float*)d_in[22];
  const float* b1 = (const float*)d_in[23];
  const float* W2 = (const float*)d_in[24];
  const float* b2 = (const float*)d_in[25];
  const float* g1 = (const float*)d_in[26];
  const float* be1 = (const float*)d_in[27];
  const float* g2 = (const float*)d_in[28];
  const float* be2 = (const float*)d_in[29];

  const size_t SRC_N = (size_t)BB * SS * DD;       // 3,176,448
  float* src    = (float*)d_ws;
  float* src2   = src + SRC_N;
  float* bufB   = src2 + SRC_N;
  float* coords = bufB + SRC_N;                    // 24,816
  float* bqkv   = coords + (size_t)BB * SS * 3;    // L*1152
  float2* trig  = (float2*)(bqkv + (size_t)LL * NQKV);   // B*S*24 float2
  u16* srcb  = (u16*)(trig + (size_t)BB * SS * 24);
  u16* src2b = srcb + SRC_N;
  u16* attnb = src2b + SRC_N;
  u16* qh  = attnb + SRC_N;
  const size_t QH_N = (size_t)BB * HH * SS * 64;   // 4,233,216
  u16* khb = qh + QH_N;
  u16* vtb = khb + QH_N;                           // 64*48*1088
  u16* hbf = vtb + (size_t)64 * DH * SSP;          // 12,705,792
  u16* wqkv_b = hbf + (size_t)MROWS * FFD;
  const size_t WD = (size_t)LL * DD * DD;
  const size_t WF = (size_t)LL * FFD * DD;
  u16* wo_bf = wqkv_b + (size_t)LL * NQKV * 384;
  u16* w1_bf = wo_bf + WD;
  u16* w2_bf = w1_bf + WF;

  const int M = MROWS;
  dim3 blk(256);

  build_src<<<(BB * SS * DD + 255) / 256, blk, 0, stream>>>(
      hand_t, head_t, hand_m1, head_m1, state_t, state_m1, tok_m1, tok_t, src, srcb);
  build_coords<<<(BB * SS * 3 + 255) / 256, blk, 0, stream>>>(
      c_hand_t, c_head_t, c_hand_m1, c_head_m1, tr_t, tr_m1, coords);
  build_trig<<<(BB * SS * 24 + 255) / 256, blk, 0, stream>>>(coords, trig);
  pack_qkv<<<(LL * NQKV * 96 + 255) / 256, blk, 0, stream>>>(Wq, Wk, Wv, wqkv_b);
  pack_bqkv<<<(LL * NQKV + 255) / 256, blk, 0, stream>>>(bq, bk, bv, bqkv);
  cvt_bf<<<(int)(WD / 4 + 255) / 256, blk, 0, stream>>>(Wo, wo_bf, (int)(WD / 4));
  cvt_bf<<<(int)(WF / 4 + 255) / 256, blk, 0, stream>>>(W1, w1_bf, (int)(WF / 4));
  cvt_bf<<<(int)(WF / 4 + 255) / 256, blk, 0, stream>>>(W2, w2_bf, (int)(WF / 4));
  pad_vt<<<(64 * DH * (SSP - SS) + 255) / 256, blk, 0, stream>>>(vtb);
  pad_qk<<<(64 * SS * 16 + 255) / 256, blk, 0, stream>>>(qh, khb);

  dim3 gq(DD / 64, (M + 127) / 128);       // (6, 65)
  dim3 gqkv(NQKV / 64, (M + 127) / 128);   // (18, 65)
  dim3 gf1(FFD / 64, (M + 127) / 128);     // (24, 65)
  dim3 gattn((SS + 63) / 64, HH, BB);      // (17, 8, 8)

  for (int l = 0; l < LL; ++l) {
    const u16* Wqkv_l = wqkv_b + (size_t)l * NQKV * 384;
    const u16* Wo_l = wo_bf + (size_t)l * DD * DD;
    const u16* W1_l = w1_bf + (size_t)l * FFD * DD;
    const u16* W2_l = w2_bf + (size_t)l * DD * FFD;

    gemm_as<0, 2><<<gqkv, blk, 0, stream>>>(srcb, Wqkv_l, bqkv + l * NQKV, trig,
                                            nullptr, qh, khb, vtb, M, NQKV, DD);
    attn_mfma<<<gattn, blk, 0, stream>>>(qh, khb, vtb, attnb);
    gemm_as<0, 0><<<gq, blk, 0, stream>>>(attnb, Wo_l, bo + l * DD, nullptr,
                                          bufB, nullptr, nullptr, nullptr, M, DD, DD);
    add_ln<<<M, 128, 0, stream>>>(src, bufB, g1 + l * DD, be1 + l * DD, src2, src2b);
    gemm_as<1, 1><<<gf1, blk, 0, stream>>>(src2b, W1_l, b1 + l * FFD, nullptr,
                                           nullptr, hbf, nullptr, nullptr, M, FFD, DD);
    gemm_as<0, 0><<<gq, blk, 0, stream>>>(hbf, W2_l, b2 + l * DD, nullptr,
                                          bufB, nullptr, nullptr, nullptr, M, DD, FFD);
    add_ln<<<M, 128, 0, stream>>>(src2, bufB, g2 + l * DD, be2 + l * DD, src, srcb);
  }
  copy_out<<<(BB * TT * DD + 255) / 256, blk, 0, stream>>>(src, (float*)d_out);
}